// Round 3
// baseline (6140.557 us; speedup 1.0000x reference)
//
#include <hip/hip_runtime.h>
#include <math.h>

#define Bb 8
#define Nn 1024
#define Kk 32
#define Dd 256
#define Hh 8
#define DHh 32
#define TDIMt 16
#define NBnb 32
#define HIDh 128
#define NSns 128
#define SHDs 9
#define EINe 304   // NB + TDIM + 2*NS

__device__ __forceinline__ float gelu_tanh(float x){
  float x3 = x*x*x;
  return 0.5f*x*(1.0f + tanhf(0.7978845608028654f*(x + 0.044715f*x3)));
}
__device__ __forceinline__ void fma4(float4& a, float s, const float4 w){
  a.x += s*w.x; a.y += s*w.y; a.z += s*w.z; a.w += s*w.w;
}
__device__ __forceinline__ float dot4(const float4 a, const float4 b){
  return a.x*b.x + a.y*b.y + a.z*b.z + a.w*b.w;
}

// ---------------- kNN: one wave per (b,n) ----------------
__global__ __launch_bounds__(64) void knn_kernel(const float* __restrict__ x, int* __restrict__ src){
  int bn = blockIdx.x;
  int b = bn >> 10;
  int n = bn & (Nn-1);
  int lane = threadIdx.x;
  const float* xb = x + (size_t)b*Nn*3;
  float px = xb[n*3+0], py = xb[n*3+1], pz = xb[n*3+2];
  float d2v[16];
  #pragma unroll
  for (int i=0;i<16;i++){
    int j = i*64 + lane;
    float dx = px - xb[j*3+0];
    float dy = py - xb[j*3+1];
    float dz = pz - xb[j*3+2];
    d2v[i] = dx*dx + dy*dy + dz*dz;
  }
  for (int s=0;s<Kk;s++){
    float best = 3.0e38f; int bslot = 0;
    #pragma unroll
    for (int i=0;i<16;i++){
      if (d2v[i] < best){ best = d2v[i]; bslot = i; }
    }
    int bj = bslot*64 + lane;
    #pragma unroll
    for (int off=32; off>=1; off>>=1){
      float ov = __shfl_xor(best, off);
      int   oj = __shfl_xor(bj,   off);
      if (ov < best || (ov == best && oj < bj)){ best = ov; bj = oj; }
    }
    if ((bj & 63) == lane){
      int sl = bj >> 6;
      #pragma unroll
      for (int i=0;i<16;i++) if (i==sl) d2v[i] = 3.0e38f;
    }
    if (lane == 0) src[(size_t)bn*Kk + s] = bj;
  }
}

// ---------------- embed ----------------
__global__ __launch_bounds__(256) void embed_kernel(const float* __restrict__ y, const float* __restrict__ t,
    const float* __restrict__ We, float* __restrict__ node){
  int bn = blockIdx.x; int b = bn >> 10;
  int c = threadIdx.x;
  float f0 = y[(size_t)bn*3+0], f1 = y[(size_t)bn*3+1], f2 = y[(size_t)bn*3+2];
  float a = f0*We[0*Dd+c] + f1*We[1*Dd+c] + f2*We[2*Dd+c];
  #pragma unroll
  for (int i=0;i<TDIMt;i++) a += t[b*TDIMt+i]*We[(3+i)*Dd+c];
  node[(size_t)bn*Dd + c] = a;
}

// ---------------- proj: per-node linear projections (tiled GEMM) ----------------
__global__ __launch_bounds__(256) void proj_kernel(
    const float* __restrict__ node, const float* __restrict__ t,
    const float* __restrict__ Wqg, const float* __restrict__ Wk1g,
    const float* __restrict__ bk1g, const float* __restrict__ Wvg,
    float* __restrict__ q_all, float* __restrict__ hsrc_all,
    float* __restrict__ hdst_all, float* __restrict__ vproj_all, int layer){

  __shared__ float s_n[32][264];
  const int tid = threadIdx.x;
  const int n0  = blockIdx.x*32;
  const int y   = blockIdx.y;
  const int b   = n0 >> 10;

  { int m = tid>>6; int i4 = (tid&63)*4;
    #pragma unroll
    for (int r=0;r<8;r++){
      int mm = m + r*4;
      *(float4*)&s_n[mm][i4] = *(const float4*)&node[(size_t)(n0+mm)*Dd + i4];
    } }
  __syncthreads();

  const float* wk1l = Wk1g + (size_t)layer*EINe*HIDh;
  const float* W; int wstride, rows, outw, cb; float* outp;
  if (y < 2){        W = Wqg + (size_t)layer*Dd*Dd; wstride=Dd; rows=Dd; outp=q_all; outw=Dd; cb=y*128; }
  else if (y == 2){  W = wk1l + 48*HIDh;  wstride=HIDh; rows=128; outp=hsrc_all; outw=HIDh; cb=0; }
  else if (y == 3){  W = wk1l + 176*HIDh; wstride=HIDh; rows=128; outp=hdst_all; outw=HIDh; cb=0; }
  else {             W = Wvg + (size_t)layer*265*Dd; wstride=Dd; rows=Dd; outp=vproj_all; outw=Dd; cb=(y-4)*128; }

  const int m0 = (tid>>5)*4;
  const int c0 = cb + (tid&31)*4;
  float4 acc[4];
  #pragma unroll
  for (int mm=0;mm<4;mm++) acc[mm] = make_float4(0.f,0.f,0.f,0.f);

  for (int i=0;i<rows;i+=4){
    float4 a0 = *(const float4*)&s_n[m0+0][i];
    float4 a1 = *(const float4*)&s_n[m0+1][i];
    float4 a2 = *(const float4*)&s_n[m0+2][i];
    float4 a3 = *(const float4*)&s_n[m0+3][i];
    float4 w0 = *(const float4*)&W[(size_t)(i+0)*wstride + c0];
    float4 w1 = *(const float4*)&W[(size_t)(i+1)*wstride + c0];
    float4 w2 = *(const float4*)&W[(size_t)(i+2)*wstride + c0];
    float4 w3 = *(const float4*)&W[(size_t)(i+3)*wstride + c0];
    fma4(acc[0],a0.x,w0); fma4(acc[0],a0.y,w1); fma4(acc[0],a0.z,w2); fma4(acc[0],a0.w,w3);
    fma4(acc[1],a1.x,w0); fma4(acc[1],a1.y,w1); fma4(acc[1],a1.z,w2); fma4(acc[1],a1.w,w3);
    fma4(acc[2],a2.x,w0); fma4(acc[2],a2.y,w1); fma4(acc[2],a2.z,w2); fma4(acc[2],a2.w,w3);
    fma4(acc[3],a3.x,w0); fma4(acc[3],a3.y,w1); fma4(acc[3],a3.z,w2); fma4(acc[3],a3.w,w3);
  }

  if (y == 3){
    const float* bk = bk1g + layer*HIDh;
    const float* wt = wk1l + 32*HIDh;
    float4 tb = *(const float4*)&bk[c0];
    #pragma unroll
    for (int ii=0;ii<TDIMt;ii++){
      float tv = t[b*TDIMt + ii];
      fma4(tb, tv, *(const float4*)&wt[ii*HIDh + c0]);
    }
    #pragma unroll
    for (int mm=0;mm<4;mm++){ acc[mm].x+=tb.x; acc[mm].y+=tb.y; acc[mm].z+=tb.z; acc[mm].w+=tb.w; }
  }

  #pragma unroll
  for (int mm=0;mm<4;mm++)
    *(float4*)&outp[(size_t)(n0+m0+mm)*outw + c0] = acc[mm];
}

// ---------------- qw ----------------
__global__ __launch_bounds__(256) void qw_kernel(
    const float* __restrict__ q_all, const float* __restrict__ Wk2g,
    float* __restrict__ qw_all, int layer){
  __shared__ float s_q[32][36];
  const int tid = threadIdx.x;
  const int n0  = blockIdx.x*32;
  const int h   = blockIdx.y;
  const float* wk2l = Wk2g + (size_t)layer*HIDh*Dd;
  #pragma unroll
  for (int r=0;r<4;r++){
    int idx = tid + r*256;
    int m = idx>>5, d = idx&31;
    s_q[m][d] = q_all[(size_t)(n0+m)*Dd + h*DHh + d];
  }
  __syncthreads();
  const int m0 = (tid>>5)*4;
  const int c0 = (tid&31)*4;
  float4 acc[4];
  #pragma unroll
  for (int mm=0;mm<4;mm++) acc[mm] = make_float4(0.f,0.f,0.f,0.f);
  #pragma unroll
  for (int d=0; d<DHh; d+=4){
    float4 a0 = *(const float4*)&s_q[m0+0][d];
    float4 a1 = *(const float4*)&s_q[m0+1][d];
    float4 a2 = *(const float4*)&s_q[m0+2][d];
    float4 a3 = *(const float4*)&s_q[m0+3][d];
    float4 w0 = *(const float4*)&wk2l[(size_t)(c0+0)*Dd + h*DHh + d];
    float4 w1 = *(const float4*)&wk2l[(size_t)(c0+1)*Dd + h*DHh + d];
    float4 w2 = *(const float4*)&wk2l[(size_t)(c0+2)*Dd + h*DHh + d];
    float4 w3 = *(const float4*)&wk2l[(size_t)(c0+3)*Dd + h*DHh + d];
    acc[0].x += dot4(a0,w0); acc[0].y += dot4(a0,w1); acc[0].z += dot4(a0,w2); acc[0].w += dot4(a0,w3);
    acc[1].x += dot4(a1,w0); acc[1].y += dot4(a1,w1); acc[1].z += dot4(a1,w2); acc[1].w += dot4(a1,w3);
    acc[2].x += dot4(a2,w0); acc[2].y += dot4(a2,w1); acc[2].z += dot4(a2,w2); acc[2].w += dot4(a2,w3);
    acc[3].x += dot4(a3,w0); acc[3].y += dot4(a3,w1); acc[3].z += dot4(a3,w2); acc[3].w += dot4(a3,w3);
  }
  #pragma unroll
  for (int mm=0;mm<4;mm++)
    *(float4*)&qw_all[(size_t)(n0+m0+mm)*(HIDh*Hh) + h*HIDh + c0] = acc[mm];
}

// ---------------- attn: block per node, fully parallel phases ----------------
__global__ __launch_bounds__(256,4) void attn_kernel(
    const float* __restrict__ x, const int* __restrict__ src,
    const float* __restrict__ hsrc_all, const float* __restrict__ hdst_all,
    const float* __restrict__ vproj_all, const float* __restrict__ qw_all,
    const float* __restrict__ Wk1g, const float* __restrict__ Wvg,
    float* __restrict__ agg_all, int layer){

  __shared__ float s_rbf[Kk][36];
  __shared__ float s_sh[Kk][12];
  __shared__ float s_cut[Kk];
  __shared__ int   s_srcv[Kk];
  __shared__ float s_qw[Hh][132];
  __shared__ float s_h[Kk][132];
  __shared__ float s_alpha[Kk][9];
  __shared__ float s_poolsh[Hh][12];

  const int tid = threadIdx.x;
  const int bn  = blockIdx.x;
  const int b   = bn >> 10;
  const float* wk1rbf = Wk1g + (size_t)layer*EINe*HIDh;  // rows 0..31

  #pragma unroll
  for (int r=0;r<4;r++){
    int idx = tid + r*256;
    s_qw[idx>>7][idx&127] = qw_all[(size_t)bn*(HIDh*Hh) + idx];
  }

  // geometry: thread = (k = tid>>3, i = tid&7); 4 rbf basis per thread (+1 cut expf, redundant)
  {
    int k = tid>>3, i = tid&7;
    int j = src[(size_t)bn*Kk + k];
    if (i == 0) s_srcv[k] = j;
    float ax = x[(size_t)bn*3+0], ay = x[(size_t)bn*3+1], az = x[(size_t)bn*3+2];
    const float* xj = x + ((size_t)b*Nn + j)*3;
    float dx = ax - xj[0], dy = ay - xj[1], dz = az - xj[2];
    float rr = sqrtf(dx*dx + dy*dy + dz*dz);
    float xx = 10.0f*(1.0f - rr*0.5f);
    float cu = (xx > 0.0f) ? 1.4f*expf(-1.0f/xx) : 0.0f;
    if (i == 0) s_cut[k] = cu;
    if (i == 1){
      float inv = 1.0f / fmaxf(rr, 1e-9f);
      float ux = dx*inv, uy = dy*inv, uz = dz*inv;
      s_sh[k][0] = 1.0f;
      s_sh[k][1] = 1.7320508075688772f*ux;
      s_sh[k][2] = 1.7320508075688772f*uy;
      s_sh[k][3] = 1.7320508075688772f*uz;
      s_sh[k][4] = 3.872983346207417f*ux*uy;
      s_sh[k][5] = 3.872983346207417f*uy*uz;
      s_sh[k][6] = 1.118033988749895f*(3.0f*uz*uz - 1.0f);
      s_sh[k][7] = 3.872983346207417f*ux*uz;
      s_sh[k][8] = 1.9364916731037085f*(ux*ux - uy*uy);
    }
    float rs = rr*15.5f;      // r/step, step = 2/31
    float base = (float)(i*4);
    #pragma unroll
    for (int c=0;c<4;c++){
      float dd = rs - (base + (float)c);
      s_rbf[k][i*4+c] = expf(-dd*dd)*4.798224586623f*cu;  // sqrt(32)*0.95/1.12
    }
  }
  __syncthreads();

  // per-edge h = gelu(rbf@Wk1_rbf + hdst[n] + hsrc[src]) : 4x4 register-blocked
  {
    const int e0 = (tid>>5)*4;
    const int c0 = (tid&31)*4;
    float4 acc[4];
    #pragma unroll
    for (int mm=0;mm<4;mm++) acc[mm] = make_float4(0.f,0.f,0.f,0.f);
    #pragma unroll
    for (int ce=0; ce<NBnb; ce+=4){
      float4 a0 = *(const float4*)&s_rbf[e0+0][ce];
      float4 a1 = *(const float4*)&s_rbf[e0+1][ce];
      float4 a2 = *(const float4*)&s_rbf[e0+2][ce];
      float4 a3 = *(const float4*)&s_rbf[e0+3][ce];
      float4 w0 = *(const float4*)&wk1rbf[(ce+0)*HIDh + c0];
      float4 w1 = *(const float4*)&wk1rbf[(ce+1)*HIDh + c0];
      float4 w2 = *(const float4*)&wk1rbf[(ce+2)*HIDh + c0];
      float4 w3 = *(const float4*)&wk1rbf[(ce+3)*HIDh + c0];
      fma4(acc[0],a0.x,w0); fma4(acc[0],a0.y,w1); fma4(acc[0],a0.z,w2); fma4(acc[0],a0.w,w3);
      fma4(acc[1],a1.x,w0); fma4(acc[1],a1.y,w1); fma4(acc[1],a1.z,w2); fma4(acc[1],a1.w,w3);
      fma4(acc[2],a2.x,w0); fma4(acc[2],a2.y,w1); fma4(acc[2],a2.z,w2); fma4(acc[2],a2.w,w3);
      fma4(acc[3],a3.x,w0); fma4(acc[3],a3.y,w1); fma4(acc[3],a3.z,w2); fma4(acc[3],a3.w,w3);
    }
    float4 hd = *(const float4*)&hdst_all[(size_t)bn*HIDh + c0];
    #pragma unroll
    for (int mm=0;mm<4;mm++){
      int j = s_srcv[e0+mm];
      float4 hs = *(const float4*)&hsrc_all[((size_t)b*Nn + j)*HIDh + c0];
      float4 v;
      v.x = gelu_tanh(acc[mm].x + hd.x + hs.x);
      v.y = gelu_tanh(acc[mm].y + hd.y + hs.y);
      v.z = gelu_tanh(acc[mm].z + hd.z + hs.z);
      v.w = gelu_tanh(acc[mm].w + hd.w + hs.w);
      *(float4*)&s_h[e0+mm][c0] = v;
    }
  }
  __syncthreads();

  // logits: thread = (k = tid>>3, h = tid&7)
  {
    const int k = tid>>3, hh = tid&7;
    float a = 0.0f;
    #pragma unroll
    for (int c=0;c<HIDh;c+=4)
      a += dot4(*(const float4*)&s_h[k][c], *(const float4*)&s_qw[hh][c]);
    s_alpha[k][hh] = a*0.17677669529663687f;
  }
  __syncthreads();

  // softmax: thread = (h = tid>>5, k = tid&31), shuffle-reduce over 32-lane k-group
  {
    const int h = tid>>5, k = tid&31;
    float l = s_alpha[k][h];
    float m = l;
    #pragma unroll
    for (int off=16; off>=1; off>>=1) m = fmaxf(m, __shfl_xor(m, off));
    float w = s_cut[k]*expf(l - m);
    float ss = w;
    #pragma unroll
    for (int off=16; off>=1; off>>=1) ss += __shfl_xor(ss, off);
    s_alpha[k][h] = w/(ss + 1e-9f);
  }
  __syncthreads();

  // poolsh (72 threads) + main pooling (all threads) in one phase
  float a_main = 0.0f;
  const int h = tid>>5;
  {
    if (tid < Hh*SHDs){
      int hh = tid/SHDs, sg = tid - hh*SHDs;
      float a = 0.0f;
      #pragma unroll
      for (int k=0;k<Kk;k++) a += s_alpha[k][hh]*s_sh[k][sg];
      s_poolsh[hh][sg] = a;
    }
    #pragma unroll
    for (int k=0;k<Kk;k++)
      a_main += s_alpha[k][h]*vproj_all[((size_t)b*Nn + s_srcv[k])*Dd + tid];
  }
  __syncthreads();

  {
    const float* wvsh = Wvg + (size_t)layer*265*Dd + 256*Dd;   // rows 256..264
    #pragma unroll
    for (int sg=0;sg<SHDs;sg++) a_main += s_poolsh[h][sg]*wvsh[sg*Dd + tid];
    agg_all[(size_t)bn*Dd + tid] = a_main;
  }
}

// ---------------- upd: node = act(node + agg @ Wo) ----------------
__global__ __launch_bounds__(256) void upd_kernel(
    const float* __restrict__ agg_all, const float* __restrict__ Wog,
    float* __restrict__ node, int layer){
  __shared__ float s_a[32][264];
  const int tid = threadIdx.x;
  const int n0  = blockIdx.x*32;
  const int y   = blockIdx.y;
  { int m = tid>>6; int i4 = (tid&63)*4;
    #pragma unroll
    for (int r=0;r<8;r++){
      int mm = m + r*4;
      *(float4*)&s_a[mm][i4] = *(const float4*)&agg_all[(size_t)(n0+mm)*Dd + i4];
    } }
  __syncthreads();
  const float* W = Wog + (size_t)layer*Dd*Dd;
  const int m0 = (tid>>5)*4;
  const int c0 = y*128 + (tid&31)*4;
  float4 acc[4];
  #pragma unroll
  for (int mm=0;mm<4;mm++) acc[mm] = make_float4(0.f,0.f,0.f,0.f);
  for (int i=0;i<Dd;i+=4){
    float4 a0 = *(const float4*)&s_a[m0+0][i];
    float4 a1 = *(const float4*)&s_a[m0+1][i];
    float4 a2 = *(const float4*)&s_a[m0+2][i];
    float4 a3 = *(const float4*)&s_a[m0+3][i];
    float4 w0 = *(const float4*)&W[(size_t)(i+0)*Dd + c0];
    float4 w1 = *(const float4*)&W[(size_t)(i+1)*Dd + c0];
    float4 w2 = *(const float4*)&W[(size_t)(i+2)*Dd + c0];
    float4 w3 = *(const float4*)&W[(size_t)(i+3)*Dd + c0];
    fma4(acc[0],a0.x,w0); fma4(acc[0],a0.y,w1); fma4(acc[0],a0.z,w2); fma4(acc[0],a0.w,w3);
    fma4(acc[1],a1.x,w0); fma4(acc[1],a1.y,w1); fma4(acc[1],a1.z,w2); fma4(acc[1],a1.w,w3);
    fma4(acc[2],a2.x,w0); fma4(acc[2],a2.y,w1); fma4(acc[2],a2.z,w2); fma4(acc[2],a2.w,w3);
    fma4(acc[3],a3.x,w0); fma4(acc[3],a3.y,w1); fma4(acc[3],a3.z,w2); fma4(acc[3],a3.w,w3);
  }
  #pragma unroll
  for (int mm=0;mm<4;mm++){
    float4 res = *(const float4*)&node[(size_t)(n0+m0+mm)*Dd + c0];
    float4 v = make_float4(res.x+acc[mm].x, res.y+acc[mm].y, res.z+acc[mm].z, res.w+acc[mm].w);
    if (c0 < 64){ v.x=gelu_tanh(v.x); v.y=gelu_tanh(v.y); v.z=gelu_tanh(v.z); v.w=gelu_tanh(v.w); }
    else if (c0 < NSns){ v.x=tanhf(v.x); v.y=tanhf(v.y); v.z=tanhf(v.z); v.w=tanhf(v.w); }
    *(float4*)&node[(size_t)(n0+m0+mm)*Dd + c0] = v;
  }
}

// ---------------- final: out = agg @ Wo_out ----------------
__global__ __launch_bounds__(256) void out_kernel(
    const float* __restrict__ agg_all, const float* __restrict__ Woo, float* __restrict__ out){
  const int tid = threadIdx.x;
  if (tid >= 192) return;
  const int n = blockIdx.x*64 + tid/3;
  const int c = tid - (tid/3)*3;
  float a = 0.0f;
  for (int i=0;i<Dd;i++) a += agg_all[(size_t)n*Dd + i]*Woo[i*3 + c];
  out[(size_t)n*3 + c] = a;
}

extern "C" void kernel_launch(void* const* d_in, const int* in_sizes, int n_in,
                              void* d_out, int out_size, void* d_ws, size_t ws_size,
                              hipStream_t stream){
  const float* x   = (const float*)d_in[0];
  const float* y   = (const float*)d_in[1];
  const float* t   = (const float*)d_in[2];
  const float* We  = (const float*)d_in[3];
  const float* Wk1 = (const float*)d_in[4];
  const float* bk1 = (const float*)d_in[5];
  const float* Wk2 = (const float*)d_in[6];
  const float* Wq  = (const float*)d_in[7];
  const float* Wv  = (const float*)d_in[8];
  const float* Wo  = (const float*)d_in[9];
  const float* Woo = (const float*)d_in[10];
  float* out = (float*)d_out;

  char* ws = (char*)d_ws;
  size_t off = 0;
  int* src = (int*)(ws + off);       off += (size_t)Bb*Nn*Kk*sizeof(int);
  float* node  = (float*)(ws + off); off += (size_t)Bb*Nn*Dd*sizeof(float);
  float* qbuf  = (float*)(ws + off); off += (size_t)Bb*Nn*Dd*sizeof(float);
  float* hsrc  = (float*)(ws + off); off += (size_t)Bb*Nn*HIDh*sizeof(float);
  float* hdst  = (float*)(ws + off); off += (size_t)Bb*Nn*HIDh*sizeof(float);
  float* vproj = (float*)(ws + off); off += (size_t)Bb*Nn*Dd*sizeof(float);
  float* qw    = (float*)(ws + off); off += (size_t)Bb*Nn*HIDh*Hh*sizeof(float);

  knn_kernel<<<dim3(Bb*Nn), 64, 0, stream>>>(x, src);
  embed_kernel<<<dim3(Bb*Nn), 256, 0, stream>>>(y, t, We, node);

  for (int l=0; l<4; l++){
    proj_kernel<<<dim3(Bb*Nn/32, 6), 256, 0, stream>>>(node, t, Wq, Wk1, bk1, Wv,
                                                       qbuf, hsrc, hdst, vproj, l);
    qw_kernel<<<dim3(Bb*Nn/32, 8), 256, 0, stream>>>(qbuf, Wk2, qw, l);
    attn_kernel<<<dim3(Bb*Nn), 256, 0, stream>>>(x, src, hsrc, hdst, vproj, qw, Wk1, Wv, qbuf, l);
    if (l < 3){
      upd_kernel<<<dim3(Bb*Nn/32, 2), 256, 0, stream>>>(qbuf, Wo, node, l);
    } else {
      out_kernel<<<dim3(Bb*Nn/64), 256, 0, stream>>>(qbuf, Woo, out);
    }
  }
}

// Round 4
// 1601.431 us; speedup vs baseline: 3.8344x; 3.8344x over previous
//
#include <hip/hip_runtime.h>
#include <math.h>

#define Bb 8
#define Nn 1024
#define Kk 32
#define Dd 256
#define Hh 8
#define DHh 32
#define TDIMt 16
#define NBnb 32
#define HIDh 128
#define NSns 128
#define SHDs 9
#define EINe 304   // NB + TDIM + 2*NS

__device__ __forceinline__ float gelu_tanh(float x){
  float x3 = x*x*x;
  return 0.5f*x*(1.0f + tanhf(0.7978845608028654f*(x + 0.044715f*x3)));
}
__device__ __forceinline__ void fma4(float4& a, float s, const float4 w){
  a.x += s*w.x; a.y += s*w.y; a.z += s*w.z; a.w += s*w.w;
}
__device__ __forceinline__ float dot4(const float4 a, const float4 b){
  return a.x*b.x + a.y*b.y + a.z*b.z + a.w*b.w;
}

// ---------------- kNN: one wave per (b,n) ----------------
__global__ __launch_bounds__(64) void knn_kernel(const float* __restrict__ x, int* __restrict__ src){
  int bn = blockIdx.x;
  int b = bn >> 10;
  int n = bn & (Nn-1);
  int lane = threadIdx.x;
  const float* xb = x + (size_t)b*Nn*3;
  float px = xb[n*3+0], py = xb[n*3+1], pz = xb[n*3+2];
  float d2v[16];
  #pragma unroll
  for (int i=0;i<16;i++){
    int j = i*64 + lane;
    float dx = px - xb[j*3+0];
    float dy = py - xb[j*3+1];
    float dz = pz - xb[j*3+2];
    d2v[i] = dx*dx + dy*dy + dz*dz;
  }
  for (int s=0;s<Kk;s++){
    float best = 3.0e38f; int bslot = 0;
    #pragma unroll
    for (int i=0;i<16;i++){
      if (d2v[i] < best){ best = d2v[i]; bslot = i; }
    }
    int bj = bslot*64 + lane;
    #pragma unroll
    for (int off=32; off>=1; off>>=1){
      float ov = __shfl_xor(best, off);
      int   oj = __shfl_xor(bj,   off);
      if (ov < best || (ov == best && oj < bj)){ best = ov; bj = oj; }
    }
    if ((bj & 63) == lane){
      int sl = bj >> 6;
      #pragma unroll
      for (int i=0;i<16;i++) if (i==sl) d2v[i] = 3.0e38f;
    }
    if (lane == 0) src[(size_t)bn*Kk + s] = bj;
  }
}

// ---------------- embed ----------------
__global__ __launch_bounds__(256) void embed_kernel(const float* __restrict__ y, const float* __restrict__ t,
    const float* __restrict__ We, float* __restrict__ node){
  int bn = blockIdx.x; int b = bn >> 10;
  int c = threadIdx.x;
  float f0 = y[(size_t)bn*3+0], f1 = y[(size_t)bn*3+1], f2 = y[(size_t)bn*3+2];
  float a = f0*We[0*Dd+c] + f1*We[1*Dd+c] + f2*We[2*Dd+c];
  #pragma unroll
  for (int i=0;i<TDIMt;i++) a += t[b*TDIMt+i]*We[(3+i)*Dd+c];
  node[(size_t)bn*Dd + c] = a;
}

// ---------------- proj: per-node linear projections (tiled GEMM) ----------------
__global__ __launch_bounds__(256) void proj_kernel(
    const float* __restrict__ node, const float* __restrict__ t,
    const float* __restrict__ Wqg, const float* __restrict__ Wk1g,
    const float* __restrict__ bk1g, const float* __restrict__ Wvg,
    float* __restrict__ q_all, float* __restrict__ hsrc_all,
    float* __restrict__ hdst_all, float* __restrict__ vproj_all, int layer){

  __shared__ float s_n[32][264];
  const int tid = threadIdx.x;
  const int n0  = blockIdx.x*32;
  const int y   = blockIdx.y;
  const int b   = n0 >> 10;

  { int m = tid>>6; int i4 = (tid&63)*4;
    #pragma unroll
    for (int r=0;r<8;r++){
      int mm = m + r*4;
      *(float4*)&s_n[mm][i4] = *(const float4*)&node[(size_t)(n0+mm)*Dd + i4];
    } }
  __syncthreads();

  const float* wk1l = Wk1g + (size_t)layer*EINe*HIDh;
  const float* W; int wstride, rows, outw, cb; float* outp;
  if (y < 2){        W = Wqg + (size_t)layer*Dd*Dd; wstride=Dd; rows=Dd; outp=q_all; outw=Dd; cb=y*128; }
  else if (y == 2){  W = wk1l + 48*HIDh;  wstride=HIDh; rows=128; outp=hsrc_all; outw=HIDh; cb=0; }
  else if (y == 3){  W = wk1l + 176*HIDh; wstride=HIDh; rows=128; outp=hdst_all; outw=HIDh; cb=0; }
  else {             W = Wvg + (size_t)layer*265*Dd; wstride=Dd; rows=Dd; outp=vproj_all; outw=Dd; cb=(y-4)*128; }

  const int m0 = (tid>>5)*4;
  const int c0 = cb + (tid&31)*4;
  float4 acc[4];
  #pragma unroll
  for (int mm=0;mm<4;mm++) acc[mm] = make_float4(0.f,0.f,0.f,0.f);

  for (int i=0;i<rows;i+=4){
    float4 a0 = *(const float4*)&s_n[m0+0][i];
    float4 a1 = *(const float4*)&s_n[m0+1][i];
    float4 a2 = *(const float4*)&s_n[m0+2][i];
    float4 a3 = *(const float4*)&s_n[m0+3][i];
    float4 w0 = *(const float4*)&W[(size_t)(i+0)*wstride + c0];
    float4 w1 = *(const float4*)&W[(size_t)(i+1)*wstride + c0];
    float4 w2 = *(const float4*)&W[(size_t)(i+2)*wstride + c0];
    float4 w3 = *(const float4*)&W[(size_t)(i+3)*wstride + c0];
    fma4(acc[0],a0.x,w0); fma4(acc[0],a0.y,w1); fma4(acc[0],a0.z,w2); fma4(acc[0],a0.w,w3);
    fma4(acc[1],a1.x,w0); fma4(acc[1],a1.y,w1); fma4(acc[1],a1.z,w2); fma4(acc[1],a1.w,w3);
    fma4(acc[2],a2.x,w0); fma4(acc[2],a2.y,w1); fma4(acc[2],a2.z,w2); fma4(acc[2],a2.w,w3);
    fma4(acc[3],a3.x,w0); fma4(acc[3],a3.y,w1); fma4(acc[3],a3.z,w2); fma4(acc[3],a3.w,w3);
  }

  if (y == 3){
    const float* bk = bk1g + layer*HIDh;
    const float* wt = wk1l + 32*HIDh;
    float4 tb = *(const float4*)&bk[c0];
    #pragma unroll
    for (int ii=0;ii<TDIMt;ii++){
      float tv = t[b*TDIMt + ii];
      fma4(tb, tv, *(const float4*)&wt[ii*HIDh + c0]);
    }
    #pragma unroll
    for (int mm=0;mm<4;mm++){ acc[mm].x+=tb.x; acc[mm].y+=tb.y; acc[mm].z+=tb.z; acc[mm].w+=tb.w; }
  }

  #pragma unroll
  for (int mm=0;mm<4;mm++)
    *(float4*)&outp[(size_t)(n0+m0+mm)*outw + c0] = acc[mm];
}

// ---------------- qw ----------------
__global__ __launch_bounds__(256) void qw_kernel(
    const float* __restrict__ q_all, const float* __restrict__ Wk2g,
    float* __restrict__ qw_all, int layer){
  __shared__ float s_q[32][36];
  const int tid = threadIdx.x;
  const int n0  = blockIdx.x*32;
  const int h   = blockIdx.y;
  const float* wk2l = Wk2g + (size_t)layer*HIDh*Dd;
  #pragma unroll
  for (int r=0;r<4;r++){
    int idx = tid + r*256;
    int m = idx>>5, d = idx&31;
    s_q[m][d] = q_all[(size_t)(n0+m)*Dd + h*DHh + d];
  }
  __syncthreads();
  const int m0 = (tid>>5)*4;
  const int c0 = (tid&31)*4;
  float4 acc[4];
  #pragma unroll
  for (int mm=0;mm<4;mm++) acc[mm] = make_float4(0.f,0.f,0.f,0.f);
  #pragma unroll
  for (int d=0; d<DHh; d+=4){
    float4 a0 = *(const float4*)&s_q[m0+0][d];
    float4 a1 = *(const float4*)&s_q[m0+1][d];
    float4 a2 = *(const float4*)&s_q[m0+2][d];
    float4 a3 = *(const float4*)&s_q[m0+3][d];
    float4 w0 = *(const float4*)&wk2l[(size_t)(c0+0)*Dd + h*DHh + d];
    float4 w1 = *(const float4*)&wk2l[(size_t)(c0+1)*Dd + h*DHh + d];
    float4 w2 = *(const float4*)&wk2l[(size_t)(c0+2)*Dd + h*DHh + d];
    float4 w3 = *(const float4*)&wk2l[(size_t)(c0+3)*Dd + h*DHh + d];
    acc[0].x += dot4(a0,w0); acc[0].y += dot4(a0,w1); acc[0].z += dot4(a0,w2); acc[0].w += dot4(a0,w3);
    acc[1].x += dot4(a1,w0); acc[1].y += dot4(a1,w1); acc[1].z += dot4(a1,w2); acc[1].w += dot4(a1,w3);
    acc[2].x += dot4(a2,w0); acc[2].y += dot4(a2,w1); acc[2].z += dot4(a2,w2); acc[2].w += dot4(a2,w3);
    acc[3].x += dot4(a3,w0); acc[3].y += dot4(a3,w1); acc[3].z += dot4(a3,w2); acc[3].w += dot4(a3,w3);
  }
  #pragma unroll
  for (int mm=0;mm<4;mm++)
    *(float4*)&qw_all[(size_t)(n0+m0+mm)*(HIDh*Hh) + h*HIDh + c0] = acc[mm];
}

// ---------------- attn: block per node, fully parallel phases ----------------
__global__ __launch_bounds__(256) void attn_kernel(
    const float* __restrict__ x, const int* __restrict__ src,
    const float* __restrict__ hsrc_all, const float* __restrict__ hdst_all,
    const float* __restrict__ vproj_all, const float* __restrict__ qw_all,
    const float* __restrict__ Wk1g, const float* __restrict__ Wvg,
    float* __restrict__ agg_all, int layer){

  __shared__ float s_rbf[Kk][36];
  __shared__ float s_sh[Kk][12];
  __shared__ float s_cut[Kk];
  __shared__ int   s_srcv[Kk];
  __shared__ float s_qw[Hh][132];
  __shared__ float s_h[Kk][132];
  __shared__ float s_alpha[Kk][9];
  __shared__ float s_poolsh[Hh][12];

  const int tid = threadIdx.x;
  const int bn  = blockIdx.x;
  const int b   = bn >> 10;
  const float* wk1rbf = Wk1g + (size_t)layer*EINe*HIDh;  // rows 0..31

  #pragma unroll
  for (int r=0;r<4;r++){
    int idx = tid + r*256;
    s_qw[idx>>7][idx&127] = qw_all[(size_t)bn*(HIDh*Hh) + idx];
  }

  // geometry: thread = (k = tid>>3, i = tid&7); 4 rbf basis per thread (+1 cut expf, redundant)
  {
    int k = tid>>3, i = tid&7;
    int j = src[(size_t)bn*Kk + k];
    if (i == 0) s_srcv[k] = j;
    float ax = x[(size_t)bn*3+0], ay = x[(size_t)bn*3+1], az = x[(size_t)bn*3+2];
    const float* xj = x + ((size_t)b*Nn + j)*3;
    float dx = ax - xj[0], dy = ay - xj[1], dz = az - xj[2];
    float rr = sqrtf(dx*dx + dy*dy + dz*dz);
    float xx = 10.0f*(1.0f - rr*0.5f);
    float cu = (xx > 0.0f) ? 1.4f*expf(-1.0f/xx) : 0.0f;
    if (i == 0) s_cut[k] = cu;
    if (i == 1){
      float inv = 1.0f / fmaxf(rr, 1e-9f);
      float ux = dx*inv, uy = dy*inv, uz = dz*inv;
      s_sh[k][0] = 1.0f;
      s_sh[k][1] = 1.7320508075688772f*ux;
      s_sh[k][2] = 1.7320508075688772f*uy;
      s_sh[k][3] = 1.7320508075688772f*uz;
      s_sh[k][4] = 3.872983346207417f*ux*uy;
      s_sh[k][5] = 3.872983346207417f*uy*uz;
      s_sh[k][6] = 1.118033988749895f*(3.0f*uz*uz - 1.0f);
      s_sh[k][7] = 3.872983346207417f*ux*uz;
      s_sh[k][8] = 1.9364916731037085f*(ux*ux - uy*uy);
    }
    float rs = rr*15.5f;      // r/step, step = 2/31
    float base = (float)(i*4);
    #pragma unroll
    for (int c=0;c<4;c++){
      float dd = rs - (base + (float)c);
      s_rbf[k][i*4+c] = expf(-dd*dd)*4.798224586623f*cu;  // sqrt(32)*0.95/1.12
    }
  }
  __syncthreads();

  // per-edge h = gelu(rbf@Wk1_rbf + hdst[n] + hsrc[src]) : 4x4 register-blocked
  {
    const int e0 = (tid>>5)*4;
    const int c0 = (tid&31)*4;
    float4 acc[4];
    #pragma unroll
    for (int mm=0;mm<4;mm++) acc[mm] = make_float4(0.f,0.f,0.f,0.f);
    #pragma unroll
    for (int ce=0; ce<NBnb; ce+=4){
      float4 a0 = *(const float4*)&s_rbf[e0+0][ce];
      float4 a1 = *(const float4*)&s_rbf[e0+1][ce];
      float4 a2 = *(const float4*)&s_rbf[e0+2][ce];
      float4 a3 = *(const float4*)&s_rbf[e0+3][ce];
      float4 w0 = *(const float4*)&wk1rbf[(ce+0)*HIDh + c0];
      float4 w1 = *(const float4*)&wk1rbf[(ce+1)*HIDh + c0];
      float4 w2 = *(const float4*)&wk1rbf[(ce+2)*HIDh + c0];
      float4 w3 = *(const float4*)&wk1rbf[(ce+3)*HIDh + c0];
      fma4(acc[0],a0.x,w0); fma4(acc[0],a0.y,w1); fma4(acc[0],a0.z,w2); fma4(acc[0],a0.w,w3);
      fma4(acc[1],a1.x,w0); fma4(acc[1],a1.y,w1); fma4(acc[1],a1.z,w2); fma4(acc[1],a1.w,w3);
      fma4(acc[2],a2.x,w0); fma4(acc[2],a2.y,w1); fma4(acc[2],a2.z,w2); fma4(acc[2],a2.w,w3);
      fma4(acc[3],a3.x,w0); fma4(acc[3],a3.y,w1); fma4(acc[3],a3.z,w2); fma4(acc[3],a3.w,w3);
    }
    float4 hd = *(const float4*)&hdst_all[(size_t)bn*HIDh + c0];
    #pragma unroll
    for (int mm=0;mm<4;mm++){
      int j = s_srcv[e0+mm];
      float4 hs = *(const float4*)&hsrc_all[((size_t)b*Nn + j)*HIDh + c0];
      float4 v;
      v.x = gelu_tanh(acc[mm].x + hd.x + hs.x);
      v.y = gelu_tanh(acc[mm].y + hd.y + hs.y);
      v.z = gelu_tanh(acc[mm].z + hd.z + hs.z);
      v.w = gelu_tanh(acc[mm].w + hd.w + hs.w);
      *(float4*)&s_h[e0+mm][c0] = v;
    }
  }
  __syncthreads();

  // logits: thread = (k = tid>>3, h = tid&7)
  {
    const int k = tid>>3, hh = tid&7;
    float a = 0.0f;
    #pragma unroll
    for (int c=0;c<HIDh;c+=4)
      a += dot4(*(const float4*)&s_h[k][c], *(const float4*)&s_qw[hh][c]);
    s_alpha[k][hh] = a*0.17677669529663687f;
  }
  __syncthreads();

  // softmax: thread = (h = tid>>5, k = tid&31), shuffle-reduce over 32-lane k-group
  {
    const int h = tid>>5, k = tid&31;
    float l = s_alpha[k][h];
    float m = l;
    #pragma unroll
    for (int off=16; off>=1; off>>=1) m = fmaxf(m, __shfl_xor(m, off));
    float w = s_cut[k]*expf(l - m);
    float ss = w;
    #pragma unroll
    for (int off=16; off>=1; off>>=1) ss += __shfl_xor(ss, off);
    s_alpha[k][h] = w/(ss + 1e-9f);
  }
  __syncthreads();

  // poolsh (72 threads) + main pooling (all threads) in one phase
  float a_main = 0.0f;
  const int h = tid>>5;
  {
    if (tid < Hh*SHDs){
      int hh = tid/SHDs, sg = tid - hh*SHDs;
      float a = 0.0f;
      #pragma unroll
      for (int k=0;k<Kk;k++) a += s_alpha[k][hh]*s_sh[k][sg];
      s_poolsh[hh][sg] = a;
    }
    #pragma unroll
    for (int k=0;k<Kk;k++)
      a_main += s_alpha[k][h]*vproj_all[((size_t)b*Nn + s_srcv[k])*Dd + tid];
  }
  __syncthreads();

  {
    const float* wvsh = Wvg + (size_t)layer*265*Dd + 256*Dd;   // rows 256..264
    #pragma unroll
    for (int sg=0;sg<SHDs;sg++) a_main += s_poolsh[h][sg]*wvsh[sg*Dd + tid];
    agg_all[(size_t)bn*Dd + tid] = a_main;
  }
}

// ---------------- upd: node = act(node + agg @ Wo) ----------------
__global__ __launch_bounds__(256) void upd_kernel(
    const float* __restrict__ agg_all, const float* __restrict__ Wog,
    float* __restrict__ node, int layer){
  __shared__ float s_a[32][264];
  const int tid = threadIdx.x;
  const int n0  = blockIdx.x*32;
  const int y   = blockIdx.y;
  { int m = tid>>6; int i4 = (tid&63)*4;
    #pragma unroll
    for (int r=0;r<8;r++){
      int mm = m + r*4;
      *(float4*)&s_a[mm][i4] = *(const float4*)&agg_all[(size_t)(n0+mm)*Dd + i4];
    } }
  __syncthreads();
  const float* W = Wog + (size_t)layer*Dd*Dd;
  const int m0 = (tid>>5)*4;
  const int c0 = y*128 + (tid&31)*4;
  float4 acc[4];
  #pragma unroll
  for (int mm=0;mm<4;mm++) acc[mm] = make_float4(0.f,0.f,0.f,0.f);
  for (int i=0;i<Dd;i+=4){
    float4 a0 = *(const float4*)&s_a[m0+0][i];
    float4 a1 = *(const float4*)&s_a[m0+1][i];
    float4 a2 = *(const float4*)&s_a[m0+2][i];
    float4 a3 = *(const float4*)&s_a[m0+3][i];
    float4 w0 = *(const float4*)&W[(size_t)(i+0)*Dd + c0];
    float4 w1 = *(const float4*)&W[(size_t)(i+1)*Dd + c0];
    float4 w2 = *(const float4*)&W[(size_t)(i+2)*Dd + c0];
    float4 w3 = *(const float4*)&W[(size_t)(i+3)*Dd + c0];
    fma4(acc[0],a0.x,w0); fma4(acc[0],a0.y,w1); fma4(acc[0],a0.z,w2); fma4(acc[0],a0.w,w3);
    fma4(acc[1],a1.x,w0); fma4(acc[1],a1.y,w1); fma4(acc[1],a1.z,w2); fma4(acc[1],a1.w,w3);
    fma4(acc[2],a2.x,w0); fma4(acc[2],a2.y,w1); fma4(acc[2],a2.z,w2); fma4(acc[2],a2.w,w3);
    fma4(acc[3],a3.x,w0); fma4(acc[3],a3.y,w1); fma4(acc[3],a3.z,w2); fma4(acc[3],a3.w,w3);
  }
  #pragma unroll
  for (int mm=0;mm<4;mm++){
    float4 res = *(const float4*)&node[(size_t)(n0+m0+mm)*Dd + c0];
    float4 v = make_float4(res.x+acc[mm].x, res.y+acc[mm].y, res.z+acc[mm].z, res.w+acc[mm].w);
    if (c0 < 64){ v.x=gelu_tanh(v.x); v.y=gelu_tanh(v.y); v.z=gelu_tanh(v.z); v.w=gelu_tanh(v.w); }
    else if (c0 < NSns){ v.x=tanhf(v.x); v.y=tanhf(v.y); v.z=tanhf(v.z); v.w=tanhf(v.w); }
    *(float4*)&node[(size_t)(n0+m0+mm)*Dd + c0] = v;
  }
}

// ---------------- final: out = agg @ Wo_out ----------------
__global__ __launch_bounds__(256) void out_kernel(
    const float* __restrict__ agg_all, const float* __restrict__ Woo, float* __restrict__ out){
  const int tid = threadIdx.x;
  if (tid >= 192) return;
  const int n = blockIdx.x*64 + tid/3;
  const int c = tid - (tid/3)*3;
  float a = 0.0f;
  for (int i=0;i<Dd;i++) a += agg_all[(size_t)n*Dd + i]*Woo[i*3 + c];
  out[(size_t)n*3 + c] = a;
}

extern "C" void kernel_launch(void* const* d_in, const int* in_sizes, int n_in,
                              void* d_out, int out_size, void* d_ws, size_t ws_size,
                              hipStream_t stream){
  const float* x   = (const float*)d_in[0];
  const float* y   = (const float*)d_in[1];
  const float* t   = (const float*)d_in[2];
  const float* We  = (const float*)d_in[3];
  const float* Wk1 = (const float*)d_in[4];
  const float* bk1 = (const float*)d_in[5];
  const float* Wk2 = (const float*)d_in[6];
  const float* Wq  = (const float*)d_in[7];
  const float* Wv  = (const float*)d_in[8];
  const float* Wo  = (const float*)d_in[9];
  const float* Woo = (const float*)d_in[10];
  float* out = (float*)d_out;

  char* ws = (char*)d_ws;
  size_t off = 0;
  int* src = (int*)(ws + off);       off += (size_t)Bb*Nn*Kk*sizeof(int);
  float* node  = (float*)(ws + off); off += (size_t)Bb*Nn*Dd*sizeof(float);
  float* qbuf  = (float*)(ws + off); off += (size_t)Bb*Nn*Dd*sizeof(float);
  float* hsrc  = (float*)(ws + off); off += (size_t)Bb*Nn*HIDh*sizeof(float);
  float* hdst  = (float*)(ws + off); off += (size_t)Bb*Nn*HIDh*sizeof(float);
  float* vproj = (float*)(ws + off); off += (size_t)Bb*Nn*Dd*sizeof(float);
  float* qw    = (float*)(ws + off); off += (size_t)Bb*Nn*HIDh*Hh*sizeof(float);

  knn_kernel<<<dim3(Bb*Nn), 64, 0, stream>>>(x, src);
  embed_kernel<<<dim3(Bb*Nn), 256, 0, stream>>>(y, t, We, node);

  for (int l=0; l<4; l++){
    proj_kernel<<<dim3(Bb*Nn/32, 6), 256, 0, stream>>>(node, t, Wq, Wk1, bk1, Wv,
                                                       qbuf, hsrc, hdst, vproj, l);
    qw_kernel<<<dim3(Bb*Nn/32, 8), 256, 0, stream>>>(qbuf, Wk2, qw, l);
    attn_kernel<<<dim3(Bb*Nn), 256, 0, stream>>>(x, src, hsrc, hdst, vproj, qw, Wk1, Wv, qbuf, l);
    if (l < 3){
      upd_kernel<<<dim3(Bb*Nn/32, 2), 256, 0, stream>>>(qbuf, Wo, node, l);
    } else {
      out_kernel<<<dim3(Bb*Nn/64), 256, 0, stream>>>(qbuf, Woo, out);
    }
  }
}

// Round 5
// 890.577 us; speedup vs baseline: 6.8950x; 1.7982x over previous
//
#include <hip/hip_runtime.h>
#include <math.h>

#define Bb 8
#define Nn 1024
#define Kk 32
#define Dd 256
#define Hh 8
#define DHh 32
#define TDIMt 16
#define NBnb 32
#define HIDh 128
#define NSns 128
#define SHDs 9
#define EINe 304   // NB + TDIM + 2*NS

// fast gelu: x * sigmoid(1.5957691*(x + 0.044715 x^3))
__device__ __forceinline__ float gelu_fast(float x){
  float g = 1.5957691216057308f*(x + 0.044715f*x*x*x);
  return x*__builtin_amdgcn_rcpf(1.0f + __expf(-g));
}
// fast tanh: 1 - 2/(1+exp(2x))
__device__ __forceinline__ float tanh_fast(float x){
  return 1.0f - 2.0f*__builtin_amdgcn_rcpf(1.0f + __expf(2.0f*x));
}
__device__ __forceinline__ void fma4(float4& a, float s, const float4 w){
  a.x += s*w.x; a.y += s*w.y; a.z += s*w.z; a.w += s*w.w;
}
__device__ __forceinline__ float dot4(const float4 a, const float4 b){
  return a.x*b.x + a.y*b.y + a.z*b.z + a.w*b.w;
}

// ---------------- kNN: one wave per (b,n) ----------------
__global__ __launch_bounds__(64) void knn_kernel(const float* __restrict__ x, int* __restrict__ src){
  int bn = blockIdx.x;
  int b = bn >> 10;
  int n = bn & (Nn-1);
  int lane = threadIdx.x;
  const float* xb = x + (size_t)b*Nn*3;
  float px = xb[n*3+0], py = xb[n*3+1], pz = xb[n*3+2];
  float d2v[16];
  #pragma unroll
  for (int i=0;i<16;i++){
    int j = i*64 + lane;
    float dx = px - xb[j*3+0];
    float dy = py - xb[j*3+1];
    float dz = pz - xb[j*3+2];
    d2v[i] = dx*dx + dy*dy + dz*dz;
  }
  for (int s=0;s<Kk;s++){
    float best = 3.0e38f; int bslot = 0;
    #pragma unroll
    for (int i=0;i<16;i++){
      if (d2v[i] < best){ best = d2v[i]; bslot = i; }
    }
    int bj = bslot*64 + lane;
    #pragma unroll
    for (int off=32; off>=1; off>>=1){
      float ov = __shfl_xor(best, off);
      int   oj = __shfl_xor(bj,   off);
      if (ov < best || (ov == best && oj < bj)){ best = ov; bj = oj; }
    }
    if ((bj & 63) == lane){
      int sl = bj >> 6;
      #pragma unroll
      for (int i=0;i<16;i++) if (i==sl) d2v[i] = 3.0e38f;
    }
    if (lane == 0) src[(size_t)bn*Kk + s] = bj;
  }
}

// ---------------- embed ----------------
__global__ __launch_bounds__(256) void embed_kernel(const float* __restrict__ y, const float* __restrict__ t,
    const float* __restrict__ We, float* __restrict__ node){
  int bn = blockIdx.x; int b = bn >> 10;
  int c = threadIdx.x;
  float f0 = y[(size_t)bn*3+0], f1 = y[(size_t)bn*3+1], f2 = y[(size_t)bn*3+2];
  float a = f0*We[0*Dd+c] + f1*We[1*Dd+c] + f2*We[2*Dd+c];
  #pragma unroll
  for (int i=0;i<TDIMt;i++) a += t[b*TDIMt+i]*We[(3+i)*Dd+c];
  node[(size_t)bn*Dd + c] = a;
}

// ---------------- proj: per-node linear projections (tiled GEMM) ----------------
__global__ __launch_bounds__(256) void proj_kernel(
    const float* __restrict__ node, const float* __restrict__ t,
    const float* __restrict__ Wqg, const float* __restrict__ Wk1g,
    const float* __restrict__ bk1g, const float* __restrict__ Wvg,
    float* __restrict__ q_all, float* __restrict__ hsrc_all,
    float* __restrict__ hdst_all, float* __restrict__ vproj_all, int layer){

  __shared__ float s_n[32][264];
  const int tid = threadIdx.x;
  const int n0  = blockIdx.x*32;
  const int y   = blockIdx.y;
  const int b   = n0 >> 10;

  { int m = tid>>6; int i4 = (tid&63)*4;
    #pragma unroll
    for (int r=0;r<8;r++){
      int mm = m + r*4;
      *(float4*)&s_n[mm][i4] = *(const float4*)&node[(size_t)(n0+mm)*Dd + i4];
    } }
  __syncthreads();

  const float* wk1l = Wk1g + (size_t)layer*EINe*HIDh;
  const float* W; int wstride, rows, outw, cb; float* outp;
  if (y < 2){        W = Wqg + (size_t)layer*Dd*Dd; wstride=Dd; rows=Dd; outp=q_all; outw=Dd; cb=y*128; }
  else if (y == 2){  W = wk1l + 48*HIDh;  wstride=HIDh; rows=128; outp=hsrc_all; outw=HIDh; cb=0; }
  else if (y == 3){  W = wk1l + 176*HIDh; wstride=HIDh; rows=128; outp=hdst_all; outw=HIDh; cb=0; }
  else {             W = Wvg + (size_t)layer*265*Dd; wstride=Dd; rows=Dd; outp=vproj_all; outw=Dd; cb=(y-4)*128; }

  const int m0 = (tid>>5)*4;
  const int c0 = cb + (tid&31)*4;
  float4 acc[4];
  #pragma unroll
  for (int mm=0;mm<4;mm++) acc[mm] = make_float4(0.f,0.f,0.f,0.f);

  for (int i=0;i<rows;i+=4){
    float4 a0 = *(const float4*)&s_n[m0+0][i];
    float4 a1 = *(const float4*)&s_n[m0+1][i];
    float4 a2 = *(const float4*)&s_n[m0+2][i];
    float4 a3 = *(const float4*)&s_n[m0+3][i];
    float4 w0 = *(const float4*)&W[(size_t)(i+0)*wstride + c0];
    float4 w1 = *(const float4*)&W[(size_t)(i+1)*wstride + c0];
    float4 w2 = *(const float4*)&W[(size_t)(i+2)*wstride + c0];
    float4 w3 = *(const float4*)&W[(size_t)(i+3)*wstride + c0];
    fma4(acc[0],a0.x,w0); fma4(acc[0],a0.y,w1); fma4(acc[0],a0.z,w2); fma4(acc[0],a0.w,w3);
    fma4(acc[1],a1.x,w0); fma4(acc[1],a1.y,w1); fma4(acc[1],a1.z,w2); fma4(acc[1],a1.w,w3);
    fma4(acc[2],a2.x,w0); fma4(acc[2],a2.y,w1); fma4(acc[2],a2.z,w2); fma4(acc[2],a2.w,w3);
    fma4(acc[3],a3.x,w0); fma4(acc[3],a3.y,w1); fma4(acc[3],a3.z,w2); fma4(acc[3],a3.w,w3);
  }

  if (y == 3){
    const float* bk = bk1g + layer*HIDh;
    const float* wt = wk1l + 32*HIDh;
    float4 tb = *(const float4*)&bk[c0];
    #pragma unroll
    for (int ii=0;ii<TDIMt;ii++){
      float tv = t[b*TDIMt + ii];
      fma4(tb, tv, *(const float4*)&wt[ii*HIDh + c0]);
    }
    #pragma unroll
    for (int mm=0;mm<4;mm++){ acc[mm].x+=tb.x; acc[mm].y+=tb.y; acc[mm].z+=tb.z; acc[mm].w+=tb.w; }
  }

  #pragma unroll
  for (int mm=0;mm<4;mm++)
    *(float4*)&outp[(size_t)(n0+m0+mm)*outw + c0] = acc[mm];
}

// ---------------- qw ----------------
__global__ __launch_bounds__(256) void qw_kernel(
    const float* __restrict__ q_all, const float* __restrict__ Wk2g,
    float* __restrict__ qw_all, int layer){
  __shared__ float s_q[32][36];
  const int tid = threadIdx.x;
  const int n0  = blockIdx.x*32;
  const int h   = blockIdx.y;
  const float* wk2l = Wk2g + (size_t)layer*HIDh*Dd;
  #pragma unroll
  for (int r=0;r<4;r++){
    int idx = tid + r*256;
    int m = idx>>5, d = idx&31;
    s_q[m][d] = q_all[(size_t)(n0+m)*Dd + h*DHh + d];
  }
  __syncthreads();
  const int m0 = (tid>>5)*4;
  const int c0 = (tid&31)*4;
  float4 acc[4];
  #pragma unroll
  for (int mm=0;mm<4;mm++) acc[mm] = make_float4(0.f,0.f,0.f,0.f);
  #pragma unroll
  for (int d=0; d<DHh; d+=4){
    float4 a0 = *(const float4*)&s_q[m0+0][d];
    float4 a1 = *(const float4*)&s_q[m0+1][d];
    float4 a2 = *(const float4*)&s_q[m0+2][d];
    float4 a3 = *(const float4*)&s_q[m0+3][d];
    float4 w0 = *(const float4*)&wk2l[(size_t)(c0+0)*Dd + h*DHh + d];
    float4 w1 = *(const float4*)&wk2l[(size_t)(c0+1)*Dd + h*DHh + d];
    float4 w2 = *(const float4*)&wk2l[(size_t)(c0+2)*Dd + h*DHh + d];
    float4 w3 = *(const float4*)&wk2l[(size_t)(c0+3)*Dd + h*DHh + d];
    acc[0].x += dot4(a0,w0); acc[0].y += dot4(a0,w1); acc[0].z += dot4(a0,w2); acc[0].w += dot4(a0,w3);
    acc[1].x += dot4(a1,w0); acc[1].y += dot4(a1,w1); acc[1].z += dot4(a1,w2); acc[1].w += dot4(a1,w3);
    acc[2].x += dot4(a2,w0); acc[2].y += dot4(a2,w1); acc[2].z += dot4(a2,w2); acc[2].w += dot4(a2,w3);
    acc[3].x += dot4(a3,w0); acc[3].y += dot4(a3,w1); acc[3].z += dot4(a3,w2); acc[3].w += dot4(a3,w3);
  }
  #pragma unroll
  for (int mm=0;mm<4;mm++)
    *(float4*)&qw_all[(size_t)(n0+m0+mm)*(HIDh*Hh) + h*HIDh + c0] = acc[mm];
}

// ---------------- attn: block per node ----------------
__global__ __launch_bounds__(256) void attn_kernel(
    const float* __restrict__ x, const int* __restrict__ src,
    const float* __restrict__ hsrc_all, const float* __restrict__ hdst_all,
    const float* __restrict__ vproj_all, const float* __restrict__ qw_all,
    const float* __restrict__ Wk1g, const float* __restrict__ Wvg,
    float* __restrict__ agg_all, int layer){

  __shared__ float s_rbf[Kk][36];
  __shared__ float s_sh[Kk][12];
  __shared__ float s_cut[Kk];
  __shared__ int   s_srcv[Kk];
  __shared__ float s_qw[Hh][132];
  __shared__ float s_h[Kk][132];
  __shared__ float s_logit[Kk][8];
  __shared__ float s_poolsh[Hh][12];

  const int tid = threadIdx.x;
  const int bn  = blockIdx.x;
  const int b   = bn >> 10;
  const float* wk1rbf = Wk1g + (size_t)layer*EINe*HIDh;  // rows 0..31

  #pragma unroll
  for (int r=0;r<4;r++){
    int idx = tid + r*256;
    s_qw[idx>>7][idx&127] = qw_all[(size_t)bn*(HIDh*Hh) + idx];
  }

  // geometry: thread = (k = tid>>3, i = tid&7); 4 rbf basis per thread
  {
    int k = tid>>3, i = tid&7;
    int j = src[(size_t)bn*Kk + k];
    if (i == 0) s_srcv[k] = j;
    float ax = x[(size_t)bn*3+0], ay = x[(size_t)bn*3+1], az = x[(size_t)bn*3+2];
    const float* xj = x + ((size_t)b*Nn + j)*3;
    float dx = ax - xj[0], dy = ay - xj[1], dz = az - xj[2];
    float rr = sqrtf(dx*dx + dy*dy + dz*dz);
    float xx = 10.0f*(1.0f - rr*0.5f);
    float cu = (xx > 0.0f) ? 1.4f*__expf(-__builtin_amdgcn_rcpf(xx)) : 0.0f;
    if (i == 0) s_cut[k] = cu;
    if (i == 1){
      float inv = __builtin_amdgcn_rcpf(fmaxf(rr, 1e-9f));
      float ux = dx*inv, uy = dy*inv, uz = dz*inv;
      s_sh[k][0] = 1.0f;
      s_sh[k][1] = 1.7320508075688772f*ux;
      s_sh[k][2] = 1.7320508075688772f*uy;
      s_sh[k][3] = 1.7320508075688772f*uz;
      s_sh[k][4] = 3.872983346207417f*ux*uy;
      s_sh[k][5] = 3.872983346207417f*uy*uz;
      s_sh[k][6] = 1.118033988749895f*(3.0f*uz*uz - 1.0f);
      s_sh[k][7] = 3.872983346207417f*ux*uz;
      s_sh[k][8] = 1.9364916731037085f*(ux*ux - uy*uy);
    }
    float rs = rr*15.5f;      // r/step
    float base = (float)(i*4);
    #pragma unroll
    for (int c=0;c<4;c++){
      float dd = rs - (base + (float)c);
      s_rbf[k][i*4+c] = __expf(-dd*dd)*4.798224586623f*cu;  // sqrt(32)*0.95/1.12
    }
  }
  __syncthreads();

  // per-edge h = gelu(rbf@Wk1_rbf + hdst[n] + hsrc[src]) : 4x4 register-blocked
  {
    const int e0 = (tid>>5)*4;
    const int c0 = (tid&31)*4;
    float4 acc[4];
    #pragma unroll
    for (int mm=0;mm<4;mm++) acc[mm] = make_float4(0.f,0.f,0.f,0.f);
    #pragma unroll
    for (int ce=0; ce<NBnb; ce+=4){
      float4 a0 = *(const float4*)&s_rbf[e0+0][ce];
      float4 a1 = *(const float4*)&s_rbf[e0+1][ce];
      float4 a2 = *(const float4*)&s_rbf[e0+2][ce];
      float4 a3 = *(const float4*)&s_rbf[e0+3][ce];
      float4 w0 = *(const float4*)&wk1rbf[(ce+0)*HIDh + c0];
      float4 w1 = *(const float4*)&wk1rbf[(ce+1)*HIDh + c0];
      float4 w2 = *(const float4*)&wk1rbf[(ce+2)*HIDh + c0];
      float4 w3 = *(const float4*)&wk1rbf[(ce+3)*HIDh + c0];
      fma4(acc[0],a0.x,w0); fma4(acc[0],a0.y,w1); fma4(acc[0],a0.z,w2); fma4(acc[0],a0.w,w3);
      fma4(acc[1],a1.x,w0); fma4(acc[1],a1.y,w1); fma4(acc[1],a1.z,w2); fma4(acc[1],a1.w,w3);
      fma4(acc[2],a2.x,w0); fma4(acc[2],a2.y,w1); fma4(acc[2],a2.z,w2); fma4(acc[2],a2.w,w3);
      fma4(acc[3],a3.x,w0); fma4(acc[3],a3.y,w1); fma4(acc[3],a3.z,w2); fma4(acc[3],a3.w,w3);
    }
    float4 hd = *(const float4*)&hdst_all[(size_t)bn*HIDh + c0];
    #pragma unroll
    for (int mm=0;mm<4;mm++){
      int j = s_srcv[e0+mm];
      float4 hs = *(const float4*)&hsrc_all[((size_t)b*Nn + j)*HIDh + c0];
      float4 v;
      v.x = gelu_fast(acc[mm].x + hd.x + hs.x);
      v.y = gelu_fast(acc[mm].y + hd.y + hs.y);
      v.z = gelu_fast(acc[mm].z + hd.z + hs.z);
      v.w = gelu_fast(acc[mm].w + hd.w + hs.w);
      *(float4*)&s_h[e0+mm][c0] = v;
    }
  }
  __syncthreads();

  // logits: thread = (k = tid>>3, hh = tid&7)
  {
    const int k = tid>>3, hh = tid&7;
    float a = 0.0f;
    #pragma unroll
    for (int c=0;c<HIDh;c+=4)
      a += dot4(*(const float4*)&s_h[k][c], *(const float4*)&s_qw[hh][c]);
    s_logit[k][hh] = a*0.17677669529663687f;
  }
  __syncthreads();

  // merged softmax + pooling + SH pooling + store.
  // thread: h = tid>>5 (head for its output col j=tid), k = lane&31 (edge for softmax)
  {
    const int l = tid & 63;
    const int k = l & 31;
    const int h = tid >> 5;
    float lv = s_logit[k][h];
    float m = lv;
    #pragma unroll
    for (int off=16; off>=1; off>>=1) m = fmaxf(m, __shfl_xor(m, off));
    float w = s_cut[k]*__expf(lv - m);
    float ss = w;
    #pragma unroll
    for (int off=16; off>=1; off>>=1) ss += __shfl_xor(ss, off);
    float alpha = w*__builtin_amdgcn_rcpf(ss + 1e-9f);

    const int half = l & 32;
    const int sgi = (k < SHDs) ? k : 0;
    float a_main = 0.0f, a_sh = 0.0f;
    #pragma unroll
    for (int kk=0; kk<Kk; kk++){
      float av = __shfl(alpha, half + kk);
      int row = s_srcv[kk];
      a_main += av * vproj_all[((size_t)b*Nn + row)*Dd + tid];
      a_sh   += av * s_sh[kk][sgi];
    }
    if (k < SHDs) s_poolsh[h][k] = a_sh;

    // same-wave LDS write->read (DS ops are in-order within a wave)
    const float* wvsh = Wvg + (size_t)layer*265*Dd + 256*Dd;   // rows 256..264
    #pragma unroll
    for (int sg=0; sg<SHDs; sg++) a_main += s_poolsh[h][sg]*wvsh[sg*Dd + tid];
    agg_all[(size_t)bn*Dd + tid] = a_main;
  }
}

// ---------------- upd: node = act(node + agg @ Wo) ----------------
__global__ __launch_bounds__(256) void upd_kernel(
    const float* __restrict__ agg_all, const float* __restrict__ Wog,
    float* __restrict__ node, int layer){
  __shared__ float s_a[32][264];
  const int tid = threadIdx.x;
  const int n0  = blockIdx.x*32;
  const int y   = blockIdx.y;
  { int m = tid>>6; int i4 = (tid&63)*4;
    #pragma unroll
    for (int r=0;r<8;r++){
      int mm = m + r*4;
      *(float4*)&s_a[mm][i4] = *(const float4*)&agg_all[(size_t)(n0+mm)*Dd + i4];
    } }
  __syncthreads();
  const float* W = Wog + (size_t)layer*Dd*Dd;
  const int m0 = (tid>>5)*4;
  const int c0 = y*128 + (tid&31)*4;
  float4 acc[4];
  #pragma unroll
  for (int mm=0;mm<4;mm++) acc[mm] = make_float4(0.f,0.f,0.f,0.f);
  for (int i=0;i<Dd;i+=4){
    float4 a0 = *(const float4*)&s_a[m0+0][i];
    float4 a1 = *(const float4*)&s_a[m0+1][i];
    float4 a2 = *(const float4*)&s_a[m0+2][i];
    float4 a3 = *(const float4*)&s_a[m0+3][i];
    float4 w0 = *(const float4*)&W[(size_t)(i+0)*Dd + c0];
    float4 w1 = *(const float4*)&W[(size_t)(i+1)*Dd + c0];
    float4 w2 = *(const float4*)&W[(size_t)(i+2)*Dd + c0];
    float4 w3 = *(const float4*)&W[(size_t)(i+3)*Dd + c0];
    fma4(acc[0],a0.x,w0); fma4(acc[0],a0.y,w1); fma4(acc[0],a0.z,w2); fma4(acc[0],a0.w,w3);
    fma4(acc[1],a1.x,w0); fma4(acc[1],a1.y,w1); fma4(acc[1],a1.z,w2); fma4(acc[1],a1.w,w3);
    fma4(acc[2],a2.x,w0); fma4(acc[2],a2.y,w1); fma4(acc[2],a2.z,w2); fma4(acc[2],a2.w,w3);
    fma4(acc[3],a3.x,w0); fma4(acc[3],a3.y,w1); fma4(acc[3],a3.z,w2); fma4(acc[3],a3.w,w3);
  }
  #pragma unroll
  for (int mm=0;mm<4;mm++){
    float4 res = *(const float4*)&node[(size_t)(n0+m0+mm)*Dd + c0];
    float4 v = make_float4(res.x+acc[mm].x, res.y+acc[mm].y, res.z+acc[mm].z, res.w+acc[mm].w);
    if (c0 < 64){ v.x=gelu_fast(v.x); v.y=gelu_fast(v.y); v.z=gelu_fast(v.z); v.w=gelu_fast(v.w); }
    else if (c0 < NSns){ v.x=tanh_fast(v.x); v.y=tanh_fast(v.y); v.z=tanh_fast(v.z); v.w=tanh_fast(v.w); }
    *(float4*)&node[(size_t)(n0+m0+mm)*Dd + c0] = v;
  }
}

// ---------------- final: out = agg @ Wo_out ----------------
__global__ __launch_bounds__(256) void out_kernel(
    const float* __restrict__ agg_all, const float* __restrict__ Woo, float* __restrict__ out){
  const int tid = threadIdx.x;
  if (tid >= 192) return;
  const int n = blockIdx.x*64 + tid/3;
  const int c = tid - (tid/3)*3;
  float a = 0.0f;
  for (int i=0;i<Dd;i++) a += agg_all[(size_t)n*Dd + i]*Woo[i*3 + c];
  out[(size_t)n*3 + c] = a;
}

extern "C" void kernel_launch(void* const* d_in, const int* in_sizes, int n_in,
                              void* d_out, int out_size, void* d_ws, size_t ws_size,
                              hipStream_t stream){
  const float* x   = (const float*)d_in[0];
  const float* y   = (const float*)d_in[1];
  const float* t   = (const float*)d_in[2];
  const float* We  = (const float*)d_in[3];
  const float* Wk1 = (const float*)d_in[4];
  const float* bk1 = (const float*)d_in[5];
  const float* Wk2 = (const float*)d_in[6];
  const float* Wq  = (const float*)d_in[7];
  const float* Wv  = (const float*)d_in[8];
  const float* Wo  = (const float*)d_in[9];
  const float* Woo = (const float*)d_in[10];
  float* out = (float*)d_out;

  char* ws = (char*)d_ws;
  size_t off = 0;
  int* src = (int*)(ws + off);       off += (size_t)Bb*Nn*Kk*sizeof(int);
  float* node  = (float*)(ws + off); off += (size_t)Bb*Nn*Dd*sizeof(float);
  float* qbuf  = (float*)(ws + off); off += (size_t)Bb*Nn*Dd*sizeof(float);
  float* hsrc  = (float*)(ws + off); off += (size_t)Bb*Nn*HIDh*sizeof(float);
  float* hdst  = (float*)(ws + off); off += (size_t)Bb*Nn*HIDh*sizeof(float);
  float* vproj = (float*)(ws + off); off += (size_t)Bb*Nn*Dd*sizeof(float);
  float* qw    = (float*)(ws + off); off += (size_t)Bb*Nn*HIDh*Hh*sizeof(float);

  knn_kernel<<<dim3(Bb*Nn), 64, 0, stream>>>(x, src);
  embed_kernel<<<dim3(Bb*Nn), 256, 0, stream>>>(y, t, We, node);

  for (int l=0; l<4; l++){
    proj_kernel<<<dim3(Bb*Nn/32, 6), 256, 0, stream>>>(node, t, Wq, Wk1, bk1, Wv,
                                                       qbuf, hsrc, hdst, vproj, l);
    qw_kernel<<<dim3(Bb*Nn/32, 8), 256, 0, stream>>>(qbuf, Wk2, qw, l);
    attn_kernel<<<dim3(Bb*Nn), 256, 0, stream>>>(x, src, hsrc, hdst, vproj, qw, Wk1, Wv, qbuf, l);
    if (l < 3){
      upd_kernel<<<dim3(Bb*Nn/32, 2), 256, 0, stream>>>(qbuf, Wo, node, l);
    } else {
      out_kernel<<<dim3(Bb*Nn/64), 256, 0, stream>>>(qbuf, Woo, out);
    }
  }
}

// Round 6
// 722.747 us; speedup vs baseline: 8.4961x; 1.2322x over previous
//
#include <hip/hip_runtime.h>
#include <math.h>

#define Bb 8
#define Nn 1024
#define Kk 32
#define Dd 256
#define Hh 8
#define DHh 32
#define TDIMt 16
#define NBnb 32
#define HIDh 128
#define NSns 128
#define SHDs 9
#define EINe 304   // NB + TDIM + 2*NS
#define NCOLS 1536 // vproj 256 | hsrc 128 | hdst 128 | qw 1024

typedef __bf16 bf16_t;
typedef bf16_t bf16x8 __attribute__((ext_vector_type(8)));
typedef float floatx4 __attribute__((ext_vector_type(4)));

// fast gelu: x * sigmoid(1.5957691*(x + 0.044715 x^3))
__device__ __forceinline__ float gelu_fast(float x){
  float g = 1.5957691216057308f*(x + 0.044715f*x*x*x);
  return x*__builtin_amdgcn_rcpf(1.0f + __expf(-g));
}
__device__ __forceinline__ float tanh_fast(float x){
  return 1.0f - 2.0f*__builtin_amdgcn_rcpf(1.0f + __expf(2.0f*x));
}
__device__ __forceinline__ void fma4(float4& a, float s, const float4 w){
  a.x += s*w.x; a.y += s*w.y; a.z += s*w.z; a.w += s*w.w;
}
__device__ __forceinline__ float dot4(const float4 a, const float4 b){
  return a.x*b.x + a.y*b.y + a.z*b.z + a.w*b.w;
}

// ---------------- kNN: one wave per (b,n) ----------------
__global__ __launch_bounds__(64) void knn_kernel(const float* __restrict__ x, int* __restrict__ src){
  int bn = blockIdx.x;
  int b = bn >> 10;
  int n = bn & (Nn-1);
  int lane = threadIdx.x;
  const float* xb = x + (size_t)b*Nn*3;
  float px = xb[n*3+0], py = xb[n*3+1], pz = xb[n*3+2];
  float d2v[16];
  #pragma unroll
  for (int i=0;i<16;i++){
    int j = i*64 + lane;
    float dx = px - xb[j*3+0];
    float dy = py - xb[j*3+1];
    float dz = pz - xb[j*3+2];
    d2v[i] = dx*dx + dy*dy + dz*dz;
  }
  for (int s=0;s<Kk;s++){
    float best = 3.0e38f; int bslot = 0;
    #pragma unroll
    for (int i=0;i<16;i++){
      if (d2v[i] < best){ best = d2v[i]; bslot = i; }
    }
    int bj = bslot*64 + lane;
    #pragma unroll
    for (int off=32; off>=1; off>>=1){
      float ov = __shfl_xor(best, off);
      int   oj = __shfl_xor(bj,   off);
      if (ov < best || (ov == best && oj < bj)){ best = ov; bj = oj; }
    }
    if ((bj & 63) == lane){
      int sl = bj >> 6;
      #pragma unroll
      for (int i=0;i<16;i++) if (i==sl) d2v[i] = 3.0e38f;
    }
    if (lane == 0) src[(size_t)bn*Kk + s] = bj;
  }
}

// ---------------- embed ----------------
__global__ __launch_bounds__(256) void embed_kernel(const float* __restrict__ y, const float* __restrict__ t,
    const float* __restrict__ We, float* __restrict__ node, bf16_t* __restrict__ node_bf){
  int bn = blockIdx.x; int b = bn >> 10;
  int c = threadIdx.x;
  float f0 = y[(size_t)bn*3+0], f1 = y[(size_t)bn*3+1], f2 = y[(size_t)bn*3+2];
  float a = f0*We[0*Dd+c] + f1*We[1*Dd+c] + f2*We[2*Dd+c];
  #pragma unroll
  for (int i=0;i<TDIMt;i++) a += t[b*TDIMt+i]*We[(3+i)*Dd+c];
  node[(size_t)bn*Dd + c] = a;
  node_bf[(size_t)bn*Dd + c] = (bf16_t)a;
}

// ---------------- weight prep: Wt[l][col][k] bf16, cols 0..511 ----------------
__global__ __launch_bounds__(256) void wprep_kernel(const float* __restrict__ Wv,
    const float* __restrict__ Wk1, bf16_t* __restrict__ Wt){
  int l = blockIdx.x, c = blockIdx.y, k = threadIdx.x;
  const float* wk1l = Wk1 + (size_t)l*EINe*HIDh;
  float v;
  if (c < 256)       v = Wv[(size_t)l*265*Dd + (size_t)k*Dd + c];
  else if (c < 384){ int c2 = c-256; v = (k < 128) ? wk1l[(48+k)*HIDh + c2] : 0.0f; }
  else             { int c2 = c-384; v = (k < 128) ? wk1l[(176+k)*HIDh + c2] : 0.0f; }
  Wt[((size_t)l*NCOLS + c)*Dd + k] = (bf16_t)v;
}

// ---------------- weight prep: fused qw weights M[i][h*128+c] -> cols 512..1535 ----------------
__global__ __launch_bounds__(256) void wprepM_kernel(const float* __restrict__ Wq,
    const float* __restrict__ Wk2, bf16_t* __restrict__ Wt){
  int l = blockIdx.x, y = blockIdx.y, i = threadIdx.x;
  int h = y >> 7, c = y & 127;
  const float* wq  = Wq  + (size_t)l*Dd*Dd   + (size_t)i*Dd + h*DHh;
  const float* wk2 = Wk2 + (size_t)l*HIDh*Dd + (size_t)c*Dd + h*DHh;
  float a = 0.0f;
  #pragma unroll
  for (int d=0; d<DHh; d++) a += wq[d]*wk2[d];
  Wt[((size_t)l*NCOLS + 512 + y)*Dd + i] = (bf16_t)a;
}

// ---------------- weight prep: Wo transposed bf16 ----------------
__global__ __launch_bounds__(256) void wprepO_kernel(const float* __restrict__ Wo, bf16_t* __restrict__ Wto){
  int l = blockIdx.x, c = blockIdx.y, k = threadIdx.x;
  Wto[((size_t)l*Dd + c)*Dd + k] = (bf16_t)Wo[(size_t)l*Dd*Dd + (size_t)k*Dd + c];
}

// ---------------- t_hd[l][b][c] = bk1 + t@Wk1_t ----------------
__global__ __launch_bounds__(128) void tprep_kernel(const float* __restrict__ t,
    const float* __restrict__ Wk1, const float* __restrict__ bk1, float* __restrict__ t_hd){
  int l = blockIdx.x, b = blockIdx.y, c = threadIdx.x;
  const float* wk1l = Wk1 + (size_t)l*EINe*HIDh;
  float a = bk1[l*HIDh + c];
  #pragma unroll
  for (int i=0;i<TDIMt;i++) a += t[b*TDIMt+i]*wk1l[(32+i)*HIDh + c];
  t_hd[(l*Bb + b)*HIDh + c] = a;
}

// ---------------- proj GEMM: proj[8192,1536] = node_bf[8192,256] @ W_L ----------------
// cols 0..511 -> proj_out f32 (stride 512); cols 512..1535 -> qw_bf bf16 (stride 1024)
__global__ __launch_bounds__(256) void gemm_proj(const bf16_t* __restrict__ A,
    const bf16_t* __restrict__ Wt_all, float* __restrict__ proj_out,
    bf16_t* __restrict__ qw_bf, int layer){
  const int tid = threadIdx.x;
  const int wave = tid>>6, lane = tid&63;
  const int row16 = lane&15, quad = lane>>4;
  const int m_base = blockIdx.x*128 + wave*32;
  const int n_base = blockIdx.y*64;
  const bf16_t* Bw = Wt_all + (size_t)layer*NCOLS*Dd;

  floatx4 acc[2][4];
  #pragma unroll
  for (int mi=0;mi<2;mi++)
    #pragma unroll
    for (int ni=0;ni<4;ni++){ floatx4 z = {0.f,0.f,0.f,0.f}; acc[mi][ni] = z; }

  const bf16_t* a0p = A  + (size_t)(m_base + row16)*Dd + quad*8;
  const bf16_t* bp  = Bw + (size_t)(n_base + row16)*Dd + quad*8;
  #pragma unroll
  for (int ks=0; ks<8; ks++){
    bf16x8 a0 = *(const bf16x8*)(a0p + ks*32);
    bf16x8 a1 = *(const bf16x8*)(a0p + 16*Dd + ks*32);
    #pragma unroll
    for (int ni=0;ni<4;ni++){
      bf16x8 b = *(const bf16x8*)(bp + (size_t)ni*16*Dd + ks*32);
      acc[0][ni] = __builtin_amdgcn_mfma_f32_16x16x32_bf16(a0, b, acc[0][ni], 0,0,0);
      acc[1][ni] = __builtin_amdgcn_mfma_f32_16x16x32_bf16(a1, b, acc[1][ni], 0,0,0);
    }
  }

  if (blockIdx.y < 8){
    #pragma unroll
    for (int mi=0;mi<2;mi++)
      #pragma unroll
      for (int ni=0;ni<4;ni++){
        int col = n_base + ni*16 + row16;
        #pragma unroll
        for (int r=0;r<4;r++){
          int row = m_base + mi*16 + quad*4 + r;
          proj_out[(size_t)row*512 + col] = acc[mi][ni][r];
        }
      }
  } else {
    #pragma unroll
    for (int mi=0;mi<2;mi++)
      #pragma unroll
      for (int ni=0;ni<4;ni++){
        int col = n_base - 512 + ni*16 + row16;
        #pragma unroll
        for (int r=0;r<4;r++){
          int row = m_base + mi*16 + quad*4 + r;
          qw_bf[(size_t)row*1024 + col] = (bf16_t)acc[mi][ni][r];
        }
      }
  }
}

// ---------------- upd GEMM: node = act(node + agg_bf @ Wo) ----------------
__global__ __launch_bounds__(256) void gemm_upd(const bf16_t* __restrict__ A,
    const bf16_t* __restrict__ Wto, float* __restrict__ node, bf16_t* __restrict__ node_bf, int layer){
  const int tid = threadIdx.x;
  const int wave = tid>>6, lane = tid&63;
  const int row16 = lane&15, quad = lane>>4;
  const int m_base = blockIdx.x*128 + wave*32;
  const int n_base = blockIdx.y*64;
  const bf16_t* Bw = Wto + (size_t)layer*Dd*Dd;

  floatx4 acc[2][4];
  #pragma unroll
  for (int mi=0;mi<2;mi++)
    #pragma unroll
    for (int ni=0;ni<4;ni++){ floatx4 z = {0.f,0.f,0.f,0.f}; acc[mi][ni] = z; }

  const bf16_t* a0p = A  + (size_t)(m_base + row16)*Dd + quad*8;
  const bf16_t* bp  = Bw + (size_t)(n_base + row16)*Dd + quad*8;
  #pragma unroll
  for (int ks=0; ks<8; ks++){
    bf16x8 a0 = *(const bf16x8*)(a0p + ks*32);
    bf16x8 a1 = *(const bf16x8*)(a0p + 16*Dd + ks*32);
    #pragma unroll
    for (int ni=0;ni<4;ni++){
      bf16x8 b = *(const bf16x8*)(bp + (size_t)ni*16*Dd + ks*32);
      acc[0][ni] = __builtin_amdgcn_mfma_f32_16x16x32_bf16(a0, b, acc[0][ni], 0,0,0);
      acc[1][ni] = __builtin_amdgcn_mfma_f32_16x16x32_bf16(a1, b, acc[1][ni], 0,0,0);
    }
  }

  #pragma unroll
  for (int mi=0;mi<2;mi++)
    #pragma unroll
    for (int ni=0;ni<4;ni++){
      int col = n_base + ni*16 + row16;
      #pragma unroll
      for (int r=0;r<4;r++){
        int row = m_base + mi*16 + quad*4 + r;
        float v = acc[mi][ni][r] + node[(size_t)row*Dd + col];
        if (col < 64)       v = gelu_fast(v);
        else if (col < 128) v = tanh_fast(v);
        node[(size_t)row*Dd + col] = v;
        node_bf[(size_t)row*Dd + col] = (bf16_t)v;
      }
    }
}

// ---------------- attn: block per node ----------------
__global__ __launch_bounds__(256) void attn_kernel(
    const float* __restrict__ x, const int* __restrict__ src,
    const float* __restrict__ proj_out, const bf16_t* __restrict__ qw_bf,
    const float* __restrict__ t_hd, const float* __restrict__ Wvg,
    float* __restrict__ agg_all, bf16_t* __restrict__ agg_bf, int layer){

  __shared__ float s_rbf[Kk][36];
  __shared__ float s_sh[Kk][12];
  __shared__ float s_cut[Kk];
  __shared__ int   s_srcv[Kk];
  __shared__ float s_qw[Hh][132];
  __shared__ float s_h[Kk][132];
  __shared__ float s_logit[Kk][8];
  __shared__ float s_poolsh[Hh][12];

  const int tid = threadIdx.x;
  const int bn  = blockIdx.x;
  const int b   = bn >> 10;

  #pragma unroll
  for (int r=0;r<4;r++){
    int idx = tid + r*256;
    s_qw[idx>>7][idx&127] = (float)qw_bf[(size_t)bn*1024 + idx];
  }

  // geometry: thread = (k = tid>>3, i = tid&7)
  {
    int k = tid>>3, i = tid&7;
    int j = src[(size_t)bn*Kk + k];
    if (i == 0) s_srcv[k] = j;
    float ax = x[(size_t)bn*3+0], ay = x[(size_t)bn*3+1], az = x[(size_t)bn*3+2];
    const float* xj = x + ((size_t)b*Nn + j)*3;
    float dx = ax - xj[0], dy = ay - xj[1], dz = az - xj[2];
    float rr = sqrtf(dx*dx + dy*dy + dz*dz);
    float xx = 10.0f*(1.0f - rr*0.5f);
    float cu = (xx > 0.0f) ? 1.4f*__expf(-__builtin_amdgcn_rcpf(xx)) : 0.0f;
    if (i == 0) s_cut[k] = cu;
    if (i == 1){
      float inv = __builtin_amdgcn_rcpf(fmaxf(rr, 1e-9f));
      float ux = dx*inv, uy = dy*inv, uz = dz*inv;
      s_sh[k][0] = 1.0f;
      s_sh[k][1] = 1.7320508075688772f*ux;
      s_sh[k][2] = 1.7320508075688772f*uy;
      s_sh[k][3] = 1.7320508075688772f*uz;
      s_sh[k][4] = 3.872983346207417f*ux*uy;
      s_sh[k][5] = 3.872983346207417f*uy*uz;
      s_sh[k][6] = 1.118033988749895f*(3.0f*uz*uz - 1.0f);
      s_sh[k][7] = 3.872983346207417f*ux*uz;
      s_sh[k][8] = 1.9364916731037085f*(ux*ux - uy*uy);
    }
    float rs = rr*15.5f;
    float base = (float)(i*4);
    #pragma unroll
    for (int c=0;c<4;c++){
      float dd = rs - (base + (float)c);
      s_rbf[k][i*4+c] = __expf(-dd*dd)*4.798224586623f*cu;
    }
  }
  __syncthreads();

  // per-edge h = gelu(rbf@Wk1_rbf + hdst[n] + hsrc[src])  -- wk1rbf still f32 global
  {
    const int e0 = (tid>>5)*4;
    const int c0 = (tid&31)*4;
    float4 acc[4];
    #pragma unroll
    for (int mm=0;mm<4;mm++) acc[mm] = make_float4(0.f,0.f,0.f,0.f);
    // Note: rbf part of Wk1 is used from its original f32 layout via t_hd-prep pointer trick:
    // we pass Wvg for wvsh only; wk1rbf accessed through proj? No — rbf GEMM needs Wk1 rows 0..31.
    // It is passed via t_hd buffer's tail? Simpler: recompute from global Wk1 pointer stored in s? 
    // -> We keep a dedicated param-free approach: rbf weights are appended after t_hd (see launch).
    const float* wk1rbf = t_hd + 4*Bb*HIDh + (size_t)layer*NBnb*HIDh;
    #pragma unroll
    for (int ce=0; ce<NBnb; ce+=4){
      float4 a0 = *(const float4*)&s_rbf[e0+0][ce];
      float4 a1 = *(const float4*)&s_rbf[e0+1][ce];
      float4 a2 = *(const float4*)&s_rbf[e0+2][ce];
      float4 a3 = *(const float4*)&s_rbf[e0+3][ce];
      float4 w0 = *(const float4*)&wk1rbf[(ce+0)*HIDh + c0];
      float4 w1 = *(const float4*)&wk1rbf[(ce+1)*HIDh + c0];
      float4 w2 = *(const float4*)&wk1rbf[(ce+2)*HIDh + c0];
      float4 w3 = *(const float4*)&wk1rbf[(ce+3)*HIDh + c0];
      fma4(acc[0],a0.x,w0); fma4(acc[0],a0.y,w1); fma4(acc[0],a0.z,w2); fma4(acc[0],a0.w,w3);
      fma4(acc[1],a1.x,w0); fma4(acc[1],a1.y,w1); fma4(acc[1],a1.z,w2); fma4(acc[1],a1.w,w3);
      fma4(acc[2],a2.x,w0); fma4(acc[2],a2.y,w1); fma4(acc[2],a2.z,w2); fma4(acc[2],a2.w,w3);
      fma4(acc[3],a3.x,w0); fma4(acc[3],a3.y,w1); fma4(acc[3],a3.z,w2); fma4(acc[3],a3.w,w3);
    }
    float4 hd = *(const float4*)&proj_out[(size_t)bn*512 + 384 + c0];
    float4 th = *(const float4*)&t_hd[(size_t)(layer*Bb + b)*HIDh + c0];
    hd.x += th.x; hd.y += th.y; hd.z += th.z; hd.w += th.w;
    #pragma unroll
    for (int mm=0;mm<4;mm++){
      int j = s_srcv[e0+mm];
      float4 hs = *(const float4*)&proj_out[((size_t)b*Nn + j)*512 + 256 + c0];
      float4 v;
      v.x = gelu_fast(acc[mm].x + hd.x + hs.x);
      v.y = gelu_fast(acc[mm].y + hd.y + hs.y);
      v.z = gelu_fast(acc[mm].z + hd.z + hs.z);
      v.w = gelu_fast(acc[mm].w + hd.w + hs.w);
      *(float4*)&s_h[e0+mm][c0] = v;
    }
  }
  __syncthreads();

  // logits
  {
    const int k = tid>>3, hh = tid&7;
    float a = 0.0f;
    #pragma unroll
    for (int c=0;c<HIDh;c+=4)
      a += dot4(*(const float4*)&s_h[k][c], *(const float4*)&s_qw[hh][c]);
    s_logit[k][hh] = a*0.17677669529663687f;
  }
  __syncthreads();

  // merged softmax + pooling + SH pooling + store
  {
    const int l = tid & 63;
    const int k = l & 31;
    const int h = tid >> 5;
    float lv = s_logit[k][h];
    float m = lv;
    #pragma unroll
    for (int off=16; off>=1; off>>=1) m = fmaxf(m, __shfl_xor(m, off));
    float w = s_cut[k]*__expf(lv - m);
    float ss = w;
    #pragma unroll
    for (int off=16; off>=1; off>>=1) ss += __shfl_xor(ss, off);
    float alpha = w*__builtin_amdgcn_rcpf(ss + 1e-9f);

    const int half = l & 32;
    const int sgi = (k < SHDs) ? k : 0;
    float a_main = 0.0f, a_sh = 0.0f;
    #pragma unroll
    for (int kk=0; kk<Kk; kk++){
      float av = __shfl(alpha, half + kk);
      int row = s_srcv[kk];
      a_main += av * proj_out[((size_t)b*Nn + row)*512 + tid];
      a_sh   += av * s_sh[kk][sgi];
    }
    if (k < SHDs) s_poolsh[h][k] = a_sh;

    const float* wvsh = Wvg + (size_t)layer*265*Dd + 256*Dd;
    #pragma unroll
    for (int sg=0; sg<SHDs; sg++) a_main += s_poolsh[h][sg]*wvsh[sg*Dd + tid];
    agg_all[(size_t)bn*Dd + tid] = a_main;
    agg_bf[(size_t)bn*Dd + tid]  = (bf16_t)a_main;
  }
}

// copy Wk1 rbf rows (32x128 per layer) into the f32 scratch right after t_hd
__global__ __launch_bounds__(256) void rbfw_kernel(const float* __restrict__ Wk1, float* __restrict__ dst){
  int l = blockIdx.x;
  int idx = blockIdx.y*256 + threadIdx.x;   // 0..4095
  dst[(size_t)l*NBnb*HIDh + idx] = Wk1[(size_t)l*EINe*HIDh + idx];
}

// ---------------- final: out = agg @ Wo_out ----------------
__global__ __launch_bounds__(256) void out_kernel(
    const float* __restrict__ agg_all, const float* __restrict__ Woo, float* __restrict__ out){
  const int tid = threadIdx.x;
  if (tid >= 192) return;
  const int n = blockIdx.x*64 + tid/3;
  const int c = tid - (tid/3)*3;
  float a = 0.0f;
  for (int i=0;i<Dd;i++) a += agg_all[(size_t)n*Dd + i]*Woo[i*3 + c];
  out[(size_t)n*3 + c] = a;
}

extern "C" void kernel_launch(void* const* d_in, const int* in_sizes, int n_in,
                              void* d_out, int out_size, void* d_ws, size_t ws_size,
                              hipStream_t stream){
  const float* x   = (const float*)d_in[0];
  const float* y   = (const float*)d_in[1];
  const float* t   = (const float*)d_in[2];
  const float* We  = (const float*)d_in[3];
  const float* Wk1 = (const float*)d_in[4];
  const float* bk1 = (const float*)d_in[5];
  const float* Wk2 = (const float*)d_in[6];
  const float* Wq  = (const float*)d_in[7];
  const float* Wv  = (const float*)d_in[8];
  const float* Wo  = (const float*)d_in[9];
  const float* Woo = (const float*)d_in[10];
  float* out = (float*)d_out;

  char* ws = (char*)d_ws;
  size_t off = 0;
  auto take = [&](size_t bytes)->char*{ char* p = ws + off; off = (off + bytes + 255) & ~(size_t)255; return p; };

  int*    src      = (int*)   take((size_t)Bb*Nn*Kk*4);          // 1.0 MB
  float*  node     = (float*) take((size_t)Bb*Nn*Dd*4);          // 8.4 MB
  bf16_t* node_bf  = (bf16_t*)take((size_t)Bb*Nn*Dd*2);          // 4.2 MB
  float*  agg      = (float*) take((size_t)Bb*Nn*Dd*4);          // 8.4 MB
  bf16_t* agg_bf   = (bf16_t*)take((size_t)Bb*Nn*Dd*2);          // 4.2 MB
  float*  proj_out = (float*) take((size_t)Bb*Nn*512*4);         // 16.8 MB
  bf16_t* qw_bf    = (bf16_t*)take((size_t)Bb*Nn*1024*2);        // 16.8 MB
  bf16_t* Wt       = (bf16_t*)take((size_t)4*NCOLS*Dd*2);        // 3.1 MB
  bf16_t* Wto      = (bf16_t*)take((size_t)3*Dd*Dd*2);           // 0.4 MB
  float*  t_hd     = (float*) take((size_t)4*Bb*HIDh*4 + (size_t)4*NBnb*HIDh*4); // t_hd + rbf weights

  // weight prep
  wprep_kernel <<<dim3(4,512),  256, 0, stream>>>(Wv, Wk1, Wt);
  wprepM_kernel<<<dim3(4,1024), 256, 0, stream>>>(Wq, Wk2, Wt);
  wprepO_kernel<<<dim3(3,256),  256, 0, stream>>>(Wo, Wto);
  tprep_kernel <<<dim3(4,8),    128, 0, stream>>>(t, Wk1, bk1, t_hd);
  rbfw_kernel  <<<dim3(4,16),   256, 0, stream>>>(Wk1, t_hd + 4*Bb*HIDh);

  knn_kernel  <<<dim3(Bb*Nn), 64,  0, stream>>>(x, src);
  embed_kernel<<<dim3(Bb*Nn), 256, 0, stream>>>(y, t, We, node, node_bf);

  for (int l=0; l<4; l++){
    gemm_proj<<<dim3(64,24), 256, 0, stream>>>(node_bf, Wt, proj_out, qw_bf, l);
    attn_kernel<<<dim3(Bb*Nn), 256, 0, stream>>>(x, src, proj_out, qw_bf, t_hd, Wv, agg, agg_bf, l);
    if (l < 3){
      gemm_upd<<<dim3(64,4), 256, 0, stream>>>(agg_bf, Wto, node, node_bf, l);
    } else {
      out_kernel<<<dim3(Bb*Nn/64), 256, 0, stream>>>(agg, Woo, out);
    }
  }
}

// Round 7
// 635.672 us; speedup vs baseline: 9.6599x; 1.1370x over previous
//
#include <hip/hip_runtime.h>
#include <math.h>

#define Bb 8
#define Nn 1024
#define Kk 32
#define Dd 256
#define Hh 8
#define DHh 32
#define TDIMt 16
#define NBnb 32
#define HIDh 128
#define NSns 128
#define SHDs 9
#define EINe 304   // NB + TDIM + 2*NS
#define NCOLS 1536 // vproj 256 | hsrc 128 | hdst 128 | qw 1024

typedef __bf16 bf16_t;
typedef bf16_t bf16x8 __attribute__((ext_vector_type(8)));
typedef bf16_t bf16x4 __attribute__((ext_vector_type(4)));
typedef float floatx4 __attribute__((ext_vector_type(4)));

// fast gelu: x * sigmoid(1.5957691*(x + 0.044715 x^3))
__device__ __forceinline__ float gelu_fast(float x){
  float g = 1.5957691216057308f*(x + 0.044715f*x*x*x);
  return x*__builtin_amdgcn_rcpf(1.0f + __expf(-g));
}
__device__ __forceinline__ float tanh_fast(float x){
  return 1.0f - 2.0f*__builtin_amdgcn_rcpf(1.0f + __expf(2.0f*x));
}

// ---------------- kNN: one wave per (b,n) ----------------
__global__ __launch_bounds__(64) void knn_kernel(const float* __restrict__ x, int* __restrict__ src){
  int bn = blockIdx.x;
  int b = bn >> 10;
  int n = bn & (Nn-1);
  int lane = threadIdx.x;
  const float* xb = x + (size_t)b*Nn*3;
  float px = xb[n*3+0], py = xb[n*3+1], pz = xb[n*3+2];
  float d2v[16];
  #pragma unroll
  for (int i=0;i<16;i++){
    int j = i*64 + lane;
    float dx = px - xb[j*3+0];
    float dy = py - xb[j*3+1];
    float dz = pz - xb[j*3+2];
    d2v[i] = dx*dx + dy*dy + dz*dz;
  }
  for (int s=0;s<Kk;s++){
    float best = 3.0e38f; int bslot = 0;
    #pragma unroll
    for (int i=0;i<16;i++){
      if (d2v[i] < best){ best = d2v[i]; bslot = i; }
    }
    int bj = bslot*64 + lane;
    #pragma unroll
    for (int off=32; off>=1; off>>=1){
      float ov = __shfl_xor(best, off);
      int   oj = __shfl_xor(bj,   off);
      if (ov < best || (ov == best && oj < bj)){ best = ov; bj = oj; }
    }
    if ((bj & 63) == lane){
      int sl = bj >> 6;
      #pragma unroll
      for (int i=0;i<16;i++) if (i==sl) d2v[i] = 3.0e38f;
    }
    if (lane == 0) src[(size_t)bn*Kk + s] = bj;
  }
}

// ---------------- embed ----------------
__global__ __launch_bounds__(256) void embed_kernel(const float* __restrict__ y, const float* __restrict__ t,
    const float* __restrict__ We, float* __restrict__ node, bf16_t* __restrict__ node_bf){
  int bn = blockIdx.x; int b = bn >> 10;
  int c = threadIdx.x;
  float f0 = y[(size_t)bn*3+0], f1 = y[(size_t)bn*3+1], f2 = y[(size_t)bn*3+2];
  float a = f0*We[0*Dd+c] + f1*We[1*Dd+c] + f2*We[2*Dd+c];
  #pragma unroll
  for (int i=0;i<TDIMt;i++) a += t[b*TDIMt+i]*We[(3+i)*Dd+c];
  node[(size_t)bn*Dd + c] = a;
  node_bf[(size_t)bn*Dd + c] = (bf16_t)a;
}

// ---------------- weight prep: Wt[l][col][k] bf16, cols 0..511 ----------------
__global__ __launch_bounds__(256) void wprep_kernel(const float* __restrict__ Wv,
    const float* __restrict__ Wk1, bf16_t* __restrict__ Wt){
  int l = blockIdx.x, c = blockIdx.y, k = threadIdx.x;
  const float* wk1l = Wk1 + (size_t)l*EINe*HIDh;
  float v;
  if (c < 256)       v = Wv[(size_t)l*265*Dd + (size_t)k*Dd + c];
  else if (c < 384){ int c2 = c-256; v = (k < 128) ? wk1l[(48+k)*HIDh + c2] : 0.0f; }
  else             { int c2 = c-384; v = (k < 128) ? wk1l[(176+k)*HIDh + c2] : 0.0f; }
  Wt[((size_t)l*NCOLS + c)*Dd + k] = (bf16_t)v;
}

// ---------------- weight prep: fused qw weights M[i][h*128+c] -> cols 512..1535 ----------------
__global__ __launch_bounds__(256) void wprepM_kernel(const float* __restrict__ Wq,
    const float* __restrict__ Wk2, bf16_t* __restrict__ Wt){
  int l = blockIdx.x, y = blockIdx.y, i = threadIdx.x;
  int h = y >> 7, c = y & 127;
  const float* wq  = Wq  + (size_t)l*Dd*Dd   + (size_t)i*Dd + h*DHh;
  const float* wk2 = Wk2 + (size_t)l*HIDh*Dd + (size_t)c*Dd + h*DHh;
  float a = 0.0f;
  #pragma unroll
  for (int d=0; d<DHh; d++) a += wq[d]*wk2[d];
  Wt[((size_t)l*NCOLS + 512 + y)*Dd + i] = (bf16_t)a;
}

// ---------------- weight prep: Wo transposed bf16 ----------------
__global__ __launch_bounds__(256) void wprepO_kernel(const float* __restrict__ Wo, bf16_t* __restrict__ Wto){
  int l = blockIdx.x, c = blockIdx.y, k = threadIdx.x;
  Wto[((size_t)l*Dd + c)*Dd + k] = (bf16_t)Wo[(size_t)l*Dd*Dd + (size_t)k*Dd + c];
}

// ---------------- weight prep: WrbfT[l][c][k] bf16 (rbf rows of Wk1, transposed) ----------------
__global__ __launch_bounds__(32) void wprepR_kernel(const float* __restrict__ Wk1, bf16_t* __restrict__ WrbfT){
  int l = blockIdx.x, c = blockIdx.y, k = threadIdx.x;   // k < 32
  WrbfT[((size_t)l*HIDh + c)*NBnb + k] = (bf16_t)Wk1[(size_t)l*EINe*HIDh + (size_t)k*HIDh + c];
}

// ---------------- t_hd[l][b][c] = bk1 + t@Wk1_t ----------------
__global__ __launch_bounds__(128) void tprep_kernel(const float* __restrict__ t,
    const float* __restrict__ Wk1, const float* __restrict__ bk1, float* __restrict__ t_hd){
  int l = blockIdx.x, b = blockIdx.y, c = threadIdx.x;
  const float* wk1l = Wk1 + (size_t)l*EINe*HIDh;
  float a = bk1[l*HIDh + c];
  #pragma unroll
  for (int i=0;i<TDIMt;i++) a += t[b*TDIMt+i]*wk1l[(32+i)*HIDh + c];
  t_hd[(l*Bb + b)*HIDh + c] = a;
}

// ---------------- proj GEMM: proj[8192,1536] = node_bf[8192,256] @ W_L ----------------
__global__ __launch_bounds__(256) void gemm_proj(const bf16_t* __restrict__ A,
    const bf16_t* __restrict__ Wt_all, float* __restrict__ proj_out,
    bf16_t* __restrict__ qw_bf, int layer){
  const int tid = threadIdx.x;
  const int wave = tid>>6, lane = tid&63;
  const int row16 = lane&15, quad = lane>>4;
  const int m_base = blockIdx.x*128 + wave*32;
  const int n_base = blockIdx.y*64;
  const bf16_t* Bw = Wt_all + (size_t)layer*NCOLS*Dd;

  floatx4 acc[2][4];
  #pragma unroll
  for (int mi=0;mi<2;mi++)
    #pragma unroll
    for (int ni=0;ni<4;ni++){ floatx4 z = {0.f,0.f,0.f,0.f}; acc[mi][ni] = z; }

  const bf16_t* a0p = A  + (size_t)(m_base + row16)*Dd + quad*8;
  const bf16_t* bp  = Bw + (size_t)(n_base + row16)*Dd + quad*8;
  #pragma unroll
  for (int ks=0; ks<8; ks++){
    bf16x8 a0 = *(const bf16x8*)(a0p + ks*32);
    bf16x8 a1 = *(const bf16x8*)(a0p + 16*Dd + ks*32);
    #pragma unroll
    for (int ni=0;ni<4;ni++){
      bf16x8 b = *(const bf16x8*)(bp + (size_t)ni*16*Dd + ks*32);
      acc[0][ni] = __builtin_amdgcn_mfma_f32_16x16x32_bf16(a0, b, acc[0][ni], 0,0,0);
      acc[1][ni] = __builtin_amdgcn_mfma_f32_16x16x32_bf16(a1, b, acc[1][ni], 0,0,0);
    }
  }

  if (blockIdx.y < 8){
    #pragma unroll
    for (int mi=0;mi<2;mi++)
      #pragma unroll
      for (int ni=0;ni<4;ni++){
        int col = n_base + ni*16 + row16;
        #pragma unroll
        for (int r=0;r<4;r++){
          int row = m_base + mi*16 + quad*4 + r;
          proj_out[(size_t)row*512 + col] = acc[mi][ni][r];
        }
      }
  } else {
    #pragma unroll
    for (int mi=0;mi<2;mi++)
      #pragma unroll
      for (int ni=0;ni<4;ni++){
        int col = n_base - 512 + ni*16 + row16;
        #pragma unroll
        for (int r=0;r<4;r++){
          int row = m_base + mi*16 + quad*4 + r;
          qw_bf[(size_t)row*1024 + col] = (bf16_t)acc[mi][ni][r];
        }
      }
  }
}

// ---------------- upd GEMM: node = act(node + agg_bf @ Wo) ----------------
__global__ __launch_bounds__(256) void gemm_upd(const bf16_t* __restrict__ A,
    const bf16_t* __restrict__ Wto, float* __restrict__ node, bf16_t* __restrict__ node_bf, int layer){
  const int tid = threadIdx.x;
  const int wave = tid>>6, lane = tid&63;
  const int row16 = lane&15, quad = lane>>4;
  const int m_base = blockIdx.x*128 + wave*32;
  const int n_base = blockIdx.y*64;
  const bf16_t* Bw = Wto + (size_t)layer*Dd*Dd;

  floatx4 acc[2][4];
  #pragma unroll
  for (int mi=0;mi<2;mi++)
    #pragma unroll
    for (int ni=0;ni<4;ni++){ floatx4 z = {0.f,0.f,0.f,0.f}; acc[mi][ni] = z; }

  const bf16_t* a0p = A  + (size_t)(m_base + row16)*Dd + quad*8;
  const bf16_t* bp  = Bw + (size_t)(n_base + row16)*Dd + quad*8;
  #pragma unroll
  for (int ks=0; ks<8; ks++){
    bf16x8 a0 = *(const bf16x8*)(a0p + ks*32);
    bf16x8 a1 = *(const bf16x8*)(a0p + 16*Dd + ks*32);
    #pragma unroll
    for (int ni=0;ni<4;ni++){
      bf16x8 b = *(const bf16x8*)(bp + (size_t)ni*16*Dd + ks*32);
      acc[0][ni] = __builtin_amdgcn_mfma_f32_16x16x32_bf16(a0, b, acc[0][ni], 0,0,0);
      acc[1][ni] = __builtin_amdgcn_mfma_f32_16x16x32_bf16(a1, b, acc[1][ni], 0,0,0);
    }
  }

  #pragma unroll
  for (int mi=0;mi<2;mi++)
    #pragma unroll
    for (int ni=0;ni<4;ni++){
      int col = n_base + ni*16 + row16;
      #pragma unroll
      for (int r=0;r<4;r++){
        int row = m_base + mi*16 + quad*4 + r;
        float v = acc[mi][ni][r] + node[(size_t)row*Dd + col];
        if (col < 64)       v = gelu_fast(v);
        else if (col < 128) v = tanh_fast(v);
        node[(size_t)row*Dd + col] = v;
        node_bf[(size_t)row*Dd + col] = (bf16_t)v;
      }
    }
}

// ---------------- attn: block per node, MFMA h-GEMM + MFMA logits ----------------
__global__ __launch_bounds__(256) void attn_kernel(
    const float* __restrict__ x, const int* __restrict__ src,
    const float* __restrict__ proj_out, const bf16_t* __restrict__ qw_bf,
    const float* __restrict__ t_hd, const bf16_t* __restrict__ WrbfT,
    const float* __restrict__ Wvg,
    float* __restrict__ agg_all, bf16_t* __restrict__ agg_bf, int layer){

  __shared__ bf16_t s_rbf[4*32*8];      // A-fragment order: [quad][edge][j]
  __shared__ bf16_t s_h[Kk][136];       // h bf16, padded (68-word stride)
  __shared__ float  s_sh[Kk][12];
  __shared__ float  s_cut[Kk];
  __shared__ int    s_srcv[Kk];
  __shared__ float  s_hd[HIDh];
  __shared__ float  s_logit[Kk][8];
  __shared__ float  s_poolsh[Hh][12];

  const int tid = threadIdx.x;
  const int bn  = blockIdx.x;
  const int b   = bn >> 10;
  const int wave = tid>>6, lane = tid&63;
  const int row16 = lane&15, quad = lane>>4;

  // geometry: thread = (k = tid>>3, i = tid&7); 4 rbf basis per thread, packed bf16
  {
    int k = tid>>3, i = tid&7;
    int j = src[(size_t)bn*Kk + k];
    if (i == 0) s_srcv[k] = j;
    float ax = x[(size_t)bn*3+0], ay = x[(size_t)bn*3+1], az = x[(size_t)bn*3+2];
    const float* xj = x + ((size_t)b*Nn + j)*3;
    float dx = ax - xj[0], dy = ay - xj[1], dz = az - xj[2];
    float rr = sqrtf(dx*dx + dy*dy + dz*dz);
    float xx = 10.0f*(1.0f - rr*0.5f);
    float cu = (xx > 0.0f) ? 1.4f*__expf(-__builtin_amdgcn_rcpf(xx)) : 0.0f;
    if (i == 0) s_cut[k] = cu;
    if (i == 1){
      float inv = __builtin_amdgcn_rcpf(fmaxf(rr, 1e-9f));
      float ux = dx*inv, uy = dy*inv, uz = dz*inv;
      s_sh[k][0] = 1.0f;
      s_sh[k][1] = 1.7320508075688772f*ux;
      s_sh[k][2] = 1.7320508075688772f*uy;
      s_sh[k][3] = 1.7320508075688772f*uz;
      s_sh[k][4] = 3.872983346207417f*ux*uy;
      s_sh[k][5] = 3.872983346207417f*uy*uz;
      s_sh[k][6] = 1.118033988749895f*(3.0f*uz*uz - 1.0f);
      s_sh[k][7] = 3.872983346207417f*ux*uz;
      s_sh[k][8] = 1.9364916731037085f*(ux*ux - uy*uy);
    }
    float rs = rr*15.5f;
    float base = (float)(i*4);
    bf16x4 pv;
    #pragma unroll
    for (int c=0;c<4;c++){
      float dd = rs - (base + (float)c);
      pv[c] = (bf16_t)(__expf(-dd*dd)*4.798224586623f*cu);
    }
    // fragment layout: element (edge=k, basis=i*4+c) -> [i>>1][k][ (i&1)*4 + c ]
    *(bf16x4*)&s_rbf[(i>>1)*256 + k*8 + (i&1)*4] = pv;
  }
  // stage hd_total = hdst + t_hd
  if (tid < HIDh)
    s_hd[tid] = proj_out[(size_t)bn*512 + 384 + tid] + t_hd[(size_t)(layer*Bb + b)*HIDh + tid];
  __syncthreads();

  // h-GEMM via MFMA: M=32 edges, K=32 basis, N=128; wave w -> cols w*32..w*32+31
  {
    floatx4 acc[2][2];
    #pragma unroll
    for (int mi=0;mi<2;mi++)
      #pragma unroll
      for (int ni=0;ni<2;ni++){ floatx4 z = {0.f,0.f,0.f,0.f}; acc[mi][ni] = z; }
    bf16x8 a0 = *(const bf16x8*)&s_rbf[quad*256 + row16*8];
    bf16x8 a1 = *(const bf16x8*)&s_rbf[quad*256 + (16+row16)*8];
    const bf16_t* bp = WrbfT + ((size_t)layer*HIDh + wave*32 + row16)*NBnb + quad*8;
    bf16x8 b0 = *(const bf16x8*)(bp);
    bf16x8 b1 = *(const bf16x8*)(bp + 16*NBnb);
    acc[0][0] = __builtin_amdgcn_mfma_f32_16x16x32_bf16(a0, b0, acc[0][0], 0,0,0);
    acc[0][1] = __builtin_amdgcn_mfma_f32_16x16x32_bf16(a0, b1, acc[0][1], 0,0,0);
    acc[1][0] = __builtin_amdgcn_mfma_f32_16x16x32_bf16(a1, b0, acc[1][0], 0,0,0);
    acc[1][1] = __builtin_amdgcn_mfma_f32_16x16x32_bf16(a1, b1, acc[1][1], 0,0,0);
    // epilogue: D(row=edge, col=channel): + hd + hs(gather), gelu, store bf16
    #pragma unroll
    for (int ni=0;ni<2;ni++){
      int c = wave*32 + ni*16 + row16;
      float hdv = s_hd[c];
      #pragma unroll
      for (int mi=0;mi<2;mi++){
        #pragma unroll
        for (int r=0;r<4;r++){
          int e = mi*16 + quad*4 + r;
          float hs = proj_out[((size_t)b*Nn + s_srcv[e])*512 + 256 + c];
          s_h[e][c] = (bf16_t)gelu_fast(acc[mi][ni][r] + hdv + hs);
        }
      }
    }
  }
  __syncthreads();

  // logits via MFMA: M=32 edges (waves 0,1), N=16 (8 heads valid), K=128
  if (wave < 2){
    floatx4 acc = {0.f,0.f,0.f,0.f};
    const bf16_t* qp = qw_bf + (size_t)bn*1024 + row16*HIDh + quad*8;
    #pragma unroll
    for (int ks=0; ks<4; ks++){
      bf16x8 a = *(const bf16x8*)&s_h[wave*16 + row16][ks*32 + quad*8];
      bf16x8 bq = *(const bf16x8*)(qp + ks*32);
      acc = __builtin_amdgcn_mfma_f32_16x16x32_bf16(a, bq, acc, 0,0,0);
    }
    if (row16 < Hh){
      #pragma unroll
      for (int r=0;r<4;r++)
        s_logit[wave*16 + quad*4 + r][row16] = acc[r]*0.17677669529663687f;
    }
  }
  __syncthreads();

  // merged softmax + pooling + SH pooling + store
  {
    const int l = tid & 63;
    const int k = l & 31;
    const int h = tid >> 5;
    float lv = s_logit[k][h];
    float m = lv;
    #pragma unroll
    for (int off=16; off>=1; off>>=1) m = fmaxf(m, __shfl_xor(m, off));
    float w = s_cut[k]*__expf(lv - m);
    float ss = w;
    #pragma unroll
    for (int off=16; off>=1; off>>=1) ss += __shfl_xor(ss, off);
    float alpha = w*__builtin_amdgcn_rcpf(ss + 1e-9f);

    const int half = l & 32;
    const int sgi = (k < SHDs) ? k : 0;
    float a_main = 0.0f, a_sh = 0.0f;
    #pragma unroll
    for (int kk=0; kk<Kk; kk++){
      float av = __shfl(alpha, half + kk);
      int row = s_srcv[kk];
      a_main += av * proj_out[((size_t)b*Nn + row)*512 + tid];
      a_sh   += av * s_sh[kk][sgi];
    }
    if (k < SHDs) s_poolsh[h][k] = a_sh;

    const float* wvsh = Wvg + (size_t)layer*265*Dd + 256*Dd;
    #pragma unroll
    for (int sg=0; sg<SHDs; sg++) a_main += s_poolsh[h][sg]*wvsh[sg*Dd + tid];
    agg_all[(size_t)bn*Dd + tid] = a_main;
    agg_bf[(size_t)bn*Dd + tid]  = (bf16_t)a_main;
  }
}

// ---------------- final: out = agg @ Wo_out ----------------
__global__ __launch_bounds__(256) void out_kernel(
    const float* __restrict__ agg_all, const float* __restrict__ Woo, float* __restrict__ out){
  const int tid = threadIdx.x;
  if (tid >= 192) return;
  const int n = blockIdx.x*64 + tid/3;
  const int c = tid - (tid/3)*3;
  float a = 0.0f;
  for (int i=0;i<Dd;i++) a += agg_all[(size_t)n*Dd + i]*Woo[i*3 + c];
  out[(size_t)n*3 + c] = a;
}

extern "C" void kernel_launch(void* const* d_in, const int* in_sizes, int n_in,
                              void* d_out, int out_size, void* d_ws, size_t ws_size,
                              hipStream_t stream){
  const float* x   = (const float*)d_in[0];
  const float* y   = (const float*)d_in[1];
  const float* t   = (const float*)d_in[2];
  const float* We  = (const float*)d_in[3];
  const float* Wk1 = (const float*)d_in[4];
  const float* bk1 = (const float*)d_in[5];
  const float* Wk2 = (const float*)d_in[6];
  const float* Wq  = (const float*)d_in[7];
  const float* Wv  = (const float*)d_in[8];
  const float* Wo  = (const float*)d_in[9];
  const float* Woo = (const float*)d_in[10];
  float* out = (float*)d_out;

  char* ws = (char*)d_ws;
  size_t off = 0;
  auto take = [&](size_t bytes)->char*{ char* p = ws + off; off = (off + bytes + 255) & ~(size_t)255; return p; };

  int*    src      = (int*)   take((size_t)Bb*Nn*Kk*4);
  float*  node     = (float*) take((size_t)Bb*Nn*Dd*4);
  bf16_t* node_bf  = (bf16_t*)take((size_t)Bb*Nn*Dd*2);
  float*  agg      = (float*) take((size_t)Bb*Nn*Dd*4);
  bf16_t* agg_bf   = (bf16_t*)take((size_t)Bb*Nn*Dd*2);
  float*  proj_out = (float*) take((size_t)Bb*Nn*512*4);
  bf16_t* qw_bf    = (bf16_t*)take(((size_t)Bb*Nn*1024 + 2048)*2);   // +pad for B-frag overread
  bf16_t* Wt       = (bf16_t*)take((size_t)4*NCOLS*Dd*2);
  bf16_t* Wto      = (bf16_t*)take((size_t)3*Dd*Dd*2);
  bf16_t* WrbfT    = (bf16_t*)take((size_t)4*HIDh*NBnb*2);
  float*  t_hd     = (float*) take((size_t)4*Bb*HIDh*4);

  // weight prep
  wprep_kernel <<<dim3(4,512),  256, 0, stream>>>(Wv, Wk1, Wt);
  wprepM_kernel<<<dim3(4,1024), 256, 0, stream>>>(Wq, Wk2, Wt);
  wprepO_kernel<<<dim3(3,256),  256, 0, stream>>>(Wo, Wto);
  wprepR_kernel<<<dim3(4,128),  32,  0, stream>>>(Wk1, WrbfT);
  tprep_kernel <<<dim3(4,8),    128, 0, stream>>>(t, Wk1, bk1, t_hd);

  knn_kernel  <<<dim3(Bb*Nn), 64,  0, stream>>>(x, src);
  embed_kernel<<<dim3(Bb*Nn), 256, 0, stream>>>(y, t, We, node, node_bf);

  for (int l=0; l<4; l++){
    gemm_proj<<<dim3(64,24), 256, 0, stream>>>(node_bf, Wt, proj_out, qw_bf, l);
    attn_kernel<<<dim3(Bb*Nn), 256, 0, stream>>>(x, src, proj_out, qw_bf, t_hd, WrbfT, Wv, agg, agg_bf, l);
    if (l < 3){
      gemm_upd<<<dim3(64,4), 256, 0, stream>>>(agg_bf, Wto, node, node_bf, l);
    } else {
      out_kernel<<<dim3(Bb*Nn/64), 256, 0, stream>>>(agg, Woo, out);
    }
  }
}

// Round 8
// 616.058 us; speedup vs baseline: 9.9675x; 1.0318x over previous
//
#include <hip/hip_runtime.h>
#include <math.h>

#define Bb 8
#define Nn 1024
#define Kk 32
#define Dd 256
#define Hh 8
#define DHh 32
#define TDIMt 16
#define NBnb 32
#define HIDh 128
#define NSns 128
#define SHDs 9
#define EINe 304   // NB + TDIM + 2*NS
#define NCOLS 1536 // vproj 256 | hsrc 128 | hdst 128 | qw 1024

typedef __bf16 bf16_t;
typedef bf16_t bf16x8 __attribute__((ext_vector_type(8)));
typedef bf16_t bf16x4 __attribute__((ext_vector_type(4)));
typedef float floatx4 __attribute__((ext_vector_type(4)));

__device__ __forceinline__ float gelu_fast(float x){
  float g = 1.5957691216057308f*(x + 0.044715f*x*x*x);
  return x*__builtin_amdgcn_rcpf(1.0f + __expf(-g));
}
__device__ __forceinline__ float tanh_fast(float x){
  return 1.0f - 2.0f*__builtin_amdgcn_rcpf(1.0f + __expf(2.0f*x));
}

// ---------------- kNN: one wave per (b,n) ----------------
__global__ __launch_bounds__(64) void knn_kernel(const float* __restrict__ x, int* __restrict__ src){
  int bn = blockIdx.x;
  int b = bn >> 10;
  int n = bn & (Nn-1);
  int lane = threadIdx.x;
  const float* xb = x + (size_t)b*Nn*3;
  float px = xb[n*3+0], py = xb[n*3+1], pz = xb[n*3+2];
  float d2v[16];
  #pragma unroll
  for (int i=0;i<16;i++){
    int j = i*64 + lane;
    float dx = px - xb[j*3+0];
    float dy = py - xb[j*3+1];
    float dz = pz - xb[j*3+2];
    d2v[i] = dx*dx + dy*dy + dz*dz;
  }
  for (int s=0;s<Kk;s++){
    float best = 3.0e38f; int bslot = 0;
    #pragma unroll
    for (int i=0;i<16;i++){
      if (d2v[i] < best){ best = d2v[i]; bslot = i; }
    }
    int bj = bslot*64 + lane;
    #pragma unroll
    for (int off=32; off>=1; off>>=1){
      float ov = __shfl_xor(best, off);
      int   oj = __shfl_xor(bj,   off);
      if (ov < best || (ov == best && oj < bj)){ best = ov; bj = oj; }
    }
    if ((bj & 63) == lane){
      int sl = bj >> 6;
      #pragma unroll
      for (int i=0;i<16;i++) if (i==sl) d2v[i] = 3.0e38f;
    }
    if (lane == 0) src[(size_t)bn*Kk + s] = bj;
  }
}

// ---------------- embed ----------------
__global__ __launch_bounds__(256) void embed_kernel(const float* __restrict__ y, const float* __restrict__ t,
    const float* __restrict__ We, float* __restrict__ node, bf16_t* __restrict__ node_bf){
  int bn = blockIdx.x; int b = bn >> 10;
  int c = threadIdx.x;
  float f0 = y[(size_t)bn*3+0], f1 = y[(size_t)bn*3+1], f2 = y[(size_t)bn*3+2];
  float a = f0*We[0*Dd+c] + f1*We[1*Dd+c] + f2*We[2*Dd+c];
  #pragma unroll
  for (int i=0;i<TDIMt;i++) a += t[b*TDIMt+i]*We[(3+i)*Dd+c];
  node[(size_t)bn*Dd + c] = a;
  node_bf[(size_t)bn*Dd + c] = (bf16_t)a;
}

// ---------------- weight prep: Wt[l][col][k] bf16, cols 0..511 ----------------
__global__ __launch_bounds__(256) void wprep_kernel(const float* __restrict__ Wv,
    const float* __restrict__ Wk1, bf16_t* __restrict__ Wt){
  int l = blockIdx.x, c = blockIdx.y, k = threadIdx.x;
  const float* wk1l = Wk1 + (size_t)l*EINe*HIDh;
  float v;
  if (c < 256)       v = Wv[(size_t)l*265*Dd + (size_t)k*Dd + c];
  else if (c < 384){ int c2 = c-256; v = (k < 128) ? wk1l[(48+k)*HIDh + c2] : 0.0f; }
  else             { int c2 = c-384; v = (k < 128) ? wk1l[(176+k)*HIDh + c2] : 0.0f; }
  Wt[((size_t)l*NCOLS + c)*Dd + k] = (bf16_t)v;
}

// ---------------- weight prep: fused qw weights M[i][h*128+c] -> cols 512..1535 ----------------
__global__ __launch_bounds__(256) void wprepM_kernel(const float* __restrict__ Wq,
    const float* __restrict__ Wk2, bf16_t* __restrict__ Wt){
  int l = blockIdx.x, y = blockIdx.y, i = threadIdx.x;
  int h = y >> 7, c = y & 127;
  const float* wq  = Wq  + (size_t)l*Dd*Dd   + (size_t)i*Dd + h*DHh;
  const float* wk2 = Wk2 + (size_t)l*HIDh*Dd + (size_t)c*Dd + h*DHh;
  float a = 0.0f;
  #pragma unroll
  for (int d=0; d<DHh; d++) a += wq[d]*wk2[d];
  Wt[((size_t)l*NCOLS + 512 + y)*Dd + i] = (bf16_t)a;
}

// ---------------- weight prep: Wo transposed bf16 ----------------
__global__ __launch_bounds__(256) void wprepO_kernel(const float* __restrict__ Wo, bf16_t* __restrict__ Wto){
  int l = blockIdx.x, c = blockIdx.y, k = threadIdx.x;
  Wto[((size_t)l*Dd + c)*Dd + k] = (bf16_t)Wo[(size_t)l*Dd*Dd + (size_t)k*Dd + c];
}

// ---------------- weight prep: WrbfT[l][c][k] bf16 ----------------
__global__ __launch_bounds__(32) void wprepR_kernel(const float* __restrict__ Wk1, bf16_t* __restrict__ WrbfT){
  int l = blockIdx.x, c = blockIdx.y, k = threadIdx.x;   // k < 32
  WrbfT[((size_t)l*HIDh + c)*NBnb + k] = (bf16_t)Wk1[(size_t)l*EINe*HIDh + (size_t)k*HIDh + c];
}

// ---------------- t_hd[l][b][c] = bk1 + t@Wk1_t ----------------
__global__ __launch_bounds__(128) void tprep_kernel(const float* __restrict__ t,
    const float* __restrict__ Wk1, const float* __restrict__ bk1, float* __restrict__ t_hd){
  int l = blockIdx.x, b = blockIdx.y, c = threadIdx.x;
  const float* wk1l = Wk1 + (size_t)l*EINe*HIDh;
  float a = bk1[l*HIDh + c];
  #pragma unroll
  for (int i=0;i<TDIMt;i++) a += t[b*TDIMt+i]*wk1l[(32+i)*HIDh + c];
  t_hd[(l*Bb + b)*HIDh + c] = a;
}

// ---------------- proj GEMM ----------------
// by 0..3 -> vproj_bf (bf16), 4..5 -> hsrc_bf (bf16), 6..7 -> hdst_f (f32), 8..23 -> qw_bf (bf16)
__global__ __launch_bounds__(256) void gemm_proj(const bf16_t* __restrict__ A,
    const bf16_t* __restrict__ Wt_all, bf16_t* __restrict__ vproj_bf,
    bf16_t* __restrict__ hsrc_bf, float* __restrict__ hdst_f,
    bf16_t* __restrict__ qw_bf, int layer){
  const int tid = threadIdx.x;
  const int wave = tid>>6, lane = tid&63;
  const int row16 = lane&15, quad = lane>>4;
  const int m_base = blockIdx.x*128 + wave*32;
  const int n_base = blockIdx.y*64;
  const bf16_t* Bw = Wt_all + (size_t)layer*NCOLS*Dd;

  floatx4 acc[2][4];
  #pragma unroll
  for (int mi=0;mi<2;mi++)
    #pragma unroll
    for (int ni=0;ni<4;ni++){ floatx4 z = {0.f,0.f,0.f,0.f}; acc[mi][ni] = z; }

  const bf16_t* a0p = A  + (size_t)(m_base + row16)*Dd + quad*8;
  const bf16_t* bp  = Bw + (size_t)(n_base + row16)*Dd + quad*8;
  #pragma unroll
  for (int ks=0; ks<8; ks++){
    bf16x8 a0 = *(const bf16x8*)(a0p + ks*32);
    bf16x8 a1 = *(const bf16x8*)(a0p + 16*Dd + ks*32);
    #pragma unroll
    for (int ni=0;ni<4;ni++){
      bf16x8 b = *(const bf16x8*)(bp + (size_t)ni*16*Dd + ks*32);
      acc[0][ni] = __builtin_amdgcn_mfma_f32_16x16x32_bf16(a0, b, acc[0][ni], 0,0,0);
      acc[1][ni] = __builtin_amdgcn_mfma_f32_16x16x32_bf16(a1, b, acc[1][ni], 0,0,0);
    }
  }

  const int by = blockIdx.y;
  #pragma unroll
  for (int mi=0;mi<2;mi++)
    #pragma unroll
    for (int ni=0;ni<4;ni++){
      int col = n_base + ni*16 + row16;
      #pragma unroll
      for (int r=0;r<4;r++){
        int row = m_base + mi*16 + quad*4 + r;
        float v = acc[mi][ni][r];
        if (by < 4)       vproj_bf[(size_t)row*256 + col]       = (bf16_t)v;
        else if (by < 6)  hsrc_bf[(size_t)row*128 + (col-256)]  = (bf16_t)v;
        else if (by < 8)  hdst_f[(size_t)row*128 + (col-384)]   = v;
        else              qw_bf[(size_t)row*1024 + (col-512)]   = (bf16_t)v;
      }
    }
}

// ---------------- upd GEMM: node = act(node + agg_bf @ Wo) ----------------
__global__ __launch_bounds__(256) void gemm_upd(const bf16_t* __restrict__ A,
    const bf16_t* __restrict__ Wto, float* __restrict__ node, bf16_t* __restrict__ node_bf, int layer){
  const int tid = threadIdx.x;
  const int wave = tid>>6, lane = tid&63;
  const int row16 = lane&15, quad = lane>>4;
  const int m_base = blockIdx.x*128 + wave*32;
  const int n_base = blockIdx.y*64;
  const bf16_t* Bw = Wto + (size_t)layer*Dd*Dd;

  floatx4 acc[2][4];
  #pragma unroll
  for (int mi=0;mi<2;mi++)
    #pragma unroll
    for (int ni=0;ni<4;ni++){ floatx4 z = {0.f,0.f,0.f,0.f}; acc[mi][ni] = z; }

  const bf16_t* a0p = A  + (size_t)(m_base + row16)*Dd + quad*8;
  const bf16_t* bp  = Bw + (size_t)(n_base + row16)*Dd + quad*8;
  #pragma unroll
  for (int ks=0; ks<8; ks++){
    bf16x8 a0 = *(const bf16x8*)(a0p + ks*32);
    bf16x8 a1 = *(const bf16x8*)(a0p + 16*Dd + ks*32);
    #pragma unroll
    for (int ni=0;ni<4;ni++){
      bf16x8 b = *(const bf16x8*)(bp + (size_t)ni*16*Dd + ks*32);
      acc[0][ni] = __builtin_amdgcn_mfma_f32_16x16x32_bf16(a0, b, acc[0][ni], 0,0,0);
      acc[1][ni] = __builtin_amdgcn_mfma_f32_16x16x32_bf16(a1, b, acc[1][ni], 0,0,0);
    }
  }

  #pragma unroll
  for (int mi=0;mi<2;mi++)
    #pragma unroll
    for (int ni=0;ni<4;ni++){
      int col = n_base + ni*16 + row16;
      #pragma unroll
      for (int r=0;r<4;r++){
        int row = m_base + mi*16 + quad*4 + r;
        float v = acc[mi][ni][r] + node[(size_t)row*Dd + col];
        if (col < 64)       v = gelu_fast(v);
        else if (col < 128) v = tanh_fast(v);
        node[(size_t)row*Dd + col] = v;
        node_bf[(size_t)row*Dd + col] = (bf16_t)v;
      }
    }
}

// ---------------- attn: block per node, LDS-staged gathers ----------------
__global__ __launch_bounds__(256) void attn_kernel(
    const float* __restrict__ x, const int* __restrict__ src,
    const bf16_t* __restrict__ vproj_bf, const bf16_t* __restrict__ hsrc_bf,
    const float* __restrict__ hdst_f, const bf16_t* __restrict__ qw_bf,
    const float* __restrict__ t_hd, const bf16_t* __restrict__ WrbfT,
    const float* __restrict__ Wvg, const float* __restrict__ Woo,
    bf16_t* __restrict__ agg_bf, float* __restrict__ out, int layer){

  // union region: [s_rbf 2048B | s_hs 8704B] overlaid later by s_v (16896B)
  __shared__ __align__(16) char s_un[16896];
  bf16_t* s_rbf = (bf16_t*)s_un;               // 4*32*8, A-fragment order
  bf16_t* s_hs  = (bf16_t*)(s_un + 2048);      // [32][136]
  bf16_t* s_v   = (bf16_t*)s_un;               // [32][264]
  __shared__ __align__(16) bf16_t s_hbuf[32*136];
  __shared__ float s_sh[Kk][12];
  __shared__ float s_cut[Kk];
  __shared__ int   s_srcv[Kk];
  __shared__ float s_hd[HIDh];
  __shared__ float s_logit[Kk][8];
  __shared__ float s_poolsh[Hh][12];
  __shared__ float s_red[4][3];

  const int tid = threadIdx.x;
  const int bn  = blockIdx.x;
  const int b   = bn >> 10;
  const int wave = tid>>6, lane = tid&63;
  const int row16 = lane&15, quad = lane>>4;

  // P0: geometry; thread = (k = tid>>3, i = tid&7)
  {
    int k = tid>>3, i = tid&7;
    int j = src[(size_t)bn*Kk + k];
    if (i == 0) s_srcv[k] = j;
    float ax = x[(size_t)bn*3+0], ay = x[(size_t)bn*3+1], az = x[(size_t)bn*3+2];
    const float* xj = x + ((size_t)b*Nn + j)*3;
    float dx = ax - xj[0], dy = ay - xj[1], dz = az - xj[2];
    float rr = sqrtf(dx*dx + dy*dy + dz*dz);
    float xx = 10.0f*(1.0f - rr*0.5f);
    float cu = (xx > 0.0f) ? 1.4f*__expf(-__builtin_amdgcn_rcpf(xx)) : 0.0f;
    if (i == 0) s_cut[k] = cu;
    if (i == 1){
      float inv = __builtin_amdgcn_rcpf(fmaxf(rr, 1e-9f));
      float ux = dx*inv, uy = dy*inv, uz = dz*inv;
      s_sh[k][0] = 1.0f;
      s_sh[k][1] = 1.7320508075688772f*ux;
      s_sh[k][2] = 1.7320508075688772f*uy;
      s_sh[k][3] = 1.7320508075688772f*uz;
      s_sh[k][4] = 3.872983346207417f*ux*uy;
      s_sh[k][5] = 3.872983346207417f*uy*uz;
      s_sh[k][6] = 1.118033988749895f*(3.0f*uz*uz - 1.0f);
      s_sh[k][7] = 3.872983346207417f*ux*uz;
      s_sh[k][8] = 1.9364916731037085f*(ux*ux - uy*uy);
    }
    float rs = rr*15.5f;
    float base = (float)(i*4);
    bf16x4 pv;
    #pragma unroll
    for (int c=0;c<4;c++){
      float dd = rs - (base + (float)c);
      pv[c] = (bf16_t)(__expf(-dd*dd)*4.798224586623f*cu);
    }
    *(bf16x4*)(s_rbf + (i>>1)*256 + k*8 + (i&1)*4) = pv;
  }
  if (tid < HIDh)
    s_hd[tid] = hdst_f[(size_t)bn*128 + tid] + t_hd[(size_t)(layer*Bb + b)*HIDh + tid];
  __syncthreads();

  // P1: coalesced hs staging loads + h-MFMA (result stays in regs across barrier)
  bf16x8 hsv[2]; int hrow[2], hc8[2];
  #pragma unroll
  for (int rep=0;rep<2;rep++){
    int q = tid + rep*256;
    hrow[rep] = q>>4; hc8[rep] = q&15;
    hsv[rep] = *(const bf16x8*)(hsrc_bf + ((size_t)b*Nn + s_srcv[hrow[rep]])*128 + hc8[rep]*8);
  }
  floatx4 acc[2][2];
  {
    #pragma unroll
    for (int mi=0;mi<2;mi++)
      #pragma unroll
      for (int ni=0;ni<2;ni++){ floatx4 z = {0.f,0.f,0.f,0.f}; acc[mi][ni] = z; }
    bf16x8 a0 = *(const bf16x8*)(s_rbf + quad*256 + row16*8);
    bf16x8 a1 = *(const bf16x8*)(s_rbf + quad*256 + (16+row16)*8);
    const bf16_t* bp = WrbfT + ((size_t)layer*HIDh + wave*32 + row16)*NBnb + quad*8;
    bf16x8 b0 = *(const bf16x8*)(bp);
    bf16x8 b1 = *(const bf16x8*)(bp + 16*NBnb);
    acc[0][0] = __builtin_amdgcn_mfma_f32_16x16x32_bf16(a0, b0, acc[0][0], 0,0,0);
    acc[0][1] = __builtin_amdgcn_mfma_f32_16x16x32_bf16(a0, b1, acc[0][1], 0,0,0);
    acc[1][0] = __builtin_amdgcn_mfma_f32_16x16x32_bf16(a1, b0, acc[1][0], 0,0,0);
    acc[1][1] = __builtin_amdgcn_mfma_f32_16x16x32_bf16(a1, b1, acc[1][1], 0,0,0);
  }
  #pragma unroll
  for (int rep=0;rep<2;rep++)
    *(bf16x8*)(s_hs + hrow[rep]*136 + hc8[rep]*8) = hsv[rep];
  __syncthreads();

  // P2: epilogue — h = gelu(acc + hd + hs), store bf16 to s_hbuf
  #pragma unroll
  for (int ni=0;ni<2;ni++){
    int c = wave*32 + ni*16 + row16;
    float hdv = s_hd[c];
    #pragma unroll
    for (int mi=0;mi<2;mi++){
      #pragma unroll
      for (int r=0;r<4;r++){
        int e = mi*16 + quad*4 + r;
        float hs = (float)s_hs[e*136 + c];
        s_hbuf[e*136 + c] = (bf16_t)gelu_fast(acc[mi][ni][r] + hdv + hs);
      }
    }
  }
  __syncthreads();

  // P3: coalesced v staging (overlays s_rbf/s_hs) + logits MFMA on waves 0,1
  bf16x8 vv[4]; int vrow[4], vc8[4];
  #pragma unroll
  for (int rep=0;rep<4;rep++){
    int q = tid + rep*256;
    vrow[rep] = q>>5; vc8[rep] = q&31;
    vv[rep] = *(const bf16x8*)(vproj_bf + ((size_t)b*Nn + s_srcv[vrow[rep]])*256 + vc8[rep]*8);
  }
  if (wave < 2){
    floatx4 la = {0.f,0.f,0.f,0.f};
    const bf16_t* qp = qw_bf + (size_t)bn*1024 + row16*HIDh + quad*8;
    #pragma unroll
    for (int ks=0; ks<4; ks++){
      bf16x8 a = *(const bf16x8*)(s_hbuf + (wave*16 + row16)*136 + ks*32 + quad*8);
      bf16x8 bq = *(const bf16x8*)(qp + ks*32);
      la = __builtin_amdgcn_mfma_f32_16x16x32_bf16(a, bq, la, 0,0,0);
    }
    if (row16 < Hh){
      #pragma unroll
      for (int r=0;r<4;r++)
        s_logit[wave*16 + quad*4 + r][row16] = la[r]*0.17677669529663687f;
    }
  }
  #pragma unroll
  for (int rep=0;rep<4;rep++)
    *(bf16x8*)(s_v + vrow[rep]*264 + vc8[rep]*8) = vv[rep];
  __syncthreads();

  // P4: softmax + pooling (from LDS) + SH pooling + store / fused out
  {
    const int l = tid & 63;
    const int k = l & 31;
    const int h = tid >> 5;
    float lv = s_logit[k][h];
    float m = lv;
    #pragma unroll
    for (int off=16; off>=1; off>>=1) m = fmaxf(m, __shfl_xor(m, off));
    float w = s_cut[k]*__expf(lv - m);
    float ss = w;
    #pragma unroll
    for (int off=16; off>=1; off>>=1) ss += __shfl_xor(ss, off);
    float alpha = w*__builtin_amdgcn_rcpf(ss + 1e-9f);

    const int half = l & 32;
    const int sgi = (k < SHDs) ? k : 0;
    float a_main = 0.0f, a_sh = 0.0f;
    #pragma unroll
    for (int kk=0; kk<Kk; kk++){
      float av = __shfl(alpha, half + kk);
      a_main += av * (float)s_v[kk*264 + tid];
      a_sh   += av * s_sh[kk][sgi];
    }
    if (k < SHDs) s_poolsh[h][k] = a_sh;

    // same-wave LDS write->read (DS ops in-order within a wave)
    const float* wvsh = Wvg + (size_t)layer*265*Dd + 256*Dd;
    #pragma unroll
    for (int sg=0; sg<SHDs; sg++) a_main += s_poolsh[h][sg]*wvsh[sg*Dd + tid];

    if (layer < 3){
      agg_bf[(size_t)bn*Dd + tid] = (bf16_t)a_main;
    } else {
      float p0 = a_main*Woo[tid*3+0];
      float p1 = a_main*Woo[tid*3+1];
      float p2 = a_main*Woo[tid*3+2];
      #pragma unroll
      for (int off=32; off>=1; off>>=1){
        p0 += __shfl_xor(p0, off);
        p1 += __shfl_xor(p1, off);
        p2 += __shfl_xor(p2, off);
      }
      if (lane == 0){ s_red[wave][0]=p0; s_red[wave][1]=p1; s_red[wave][2]=p2; }
      __syncthreads();
      if (tid < 3)
        out[(size_t)bn*3 + tid] = s_red[0][tid]+s_red[1][tid]+s_red[2][tid]+s_red[3][tid];
    }
  }
}

extern "C" void kernel_launch(void* const* d_in, const int* in_sizes, int n_in,
                              void* d_out, int out_size, void* d_ws, size_t ws_size,
                              hipStream_t stream){
  const float* x   = (const float*)d_in[0];
  const float* y   = (const float*)d_in[1];
  const float* t   = (const float*)d_in[2];
  const float* We  = (const float*)d_in[3];
  const float* Wk1 = (const float*)d_in[4];
  const float* bk1 = (const float*)d_in[5];
  const float* Wk2 = (const float*)d_in[6];
  const float* Wq  = (const float*)d_in[7];
  const float* Wv  = (const float*)d_in[8];
  const float* Wo  = (const float*)d_in[9];
  const float* Woo = (const float*)d_in[10];
  float* out = (float*)d_out;

  char* ws = (char*)d_ws;
  size_t off = 0;
  auto take = [&](size_t bytes)->char*{ char* p = ws + off; off = (off + bytes + 255) & ~(size_t)255; return p; };

  int*    src      = (int*)   take((size_t)Bb*Nn*Kk*4);
  float*  node     = (float*) take((size_t)Bb*Nn*Dd*4);
  bf16_t* node_bf  = (bf16_t*)take((size_t)Bb*Nn*Dd*2);
  bf16_t* agg_bf   = (bf16_t*)take((size_t)Bb*Nn*Dd*2);
  bf16_t* vproj_bf = (bf16_t*)take((size_t)Bb*Nn*256*2);
  bf16_t* hsrc_bf  = (bf16_t*)take((size_t)Bb*Nn*128*2);
  float*  hdst_f   = (float*) take((size_t)Bb*Nn*128*4);
  bf16_t* qw_bf    = (bf16_t*)take(((size_t)Bb*Nn*1024 + 2048)*2);  // +pad for B-frag overread
  bf16_t* Wt       = (bf16_t*)take((size_t)4*NCOLS*Dd*2);
  bf16_t* Wto      = (bf16_t*)take((size_t)3*Dd*Dd*2);
  bf16_t* WrbfT    = (bf16_t*)take((size_t)4*HIDh*NBnb*2);
  float*  t_hd     = (float*) take((size_t)4*Bb*HIDh*4);

  // weight prep
  wprep_kernel <<<dim3(4,512),  256, 0, stream>>>(Wv, Wk1, Wt);
  wprepM_kernel<<<dim3(4,1024), 256, 0, stream>>>(Wq, Wk2, Wt);
  wprepO_kernel<<<dim3(3,256),  256, 0, stream>>>(Wo, Wto);
  wprepR_kernel<<<dim3(4,128),  32,  0, stream>>>(Wk1, WrbfT);
  tprep_kernel <<<dim3(4,8),    128, 0, stream>>>(t, Wk1, bk1, t_hd);

  knn_kernel  <<<dim3(Bb*Nn), 64,  0, stream>>>(x, src);
  embed_kernel<<<dim3(Bb*Nn), 256, 0, stream>>>(y, t, We, node, node_bf);

  for (int l=0; l<4; l++){
    gemm_proj<<<dim3(64,24), 256, 0, stream>>>(node_bf, Wt, vproj_bf, hsrc_bf, hdst_f, qw_bf, l);
    attn_kernel<<<dim3(Bb*Nn), 256, 0, stream>>>(x, src, vproj_bf, hsrc_bf, hdst_f, qw_bf,
                                                 t_hd, WrbfT, Wv, Woo, agg_bf, out, l);
    if (l < 3){
      gemm_upd<<<dim3(64,4), 256, 0, stream>>>(agg_bf, Wto, node, node_bf, l);
    }
  }
}